// Round 2
// baseline (602.563 us; speedup 1.0000x reference)
//
#include <hip/hip_runtime.h>
#include <math.h>

#define D 128

typedef short bf16x4 __attribute__((ext_vector_type(4)));
typedef short bf16x8 __attribute__((ext_vector_type(8)));
typedef float f32x4 __attribute__((ext_vector_type(4)));

__device__ __forceinline__ float4 ld4(const float* p) { return *(const float4*)p; }

__device__ __forceinline__ short f2bf(float f) {
  unsigned u = __float_as_uint(f);
  u += 0x7FFF + ((u >> 16) & 1);
  return (short)(u >> 16);
}

// ---------------- degree counting ----------------
__global__ void count_kernel(const int* __restrict__ src, const int* __restrict__ dst,
                             int* __restrict__ cnt_src, int* __restrict__ cnt_dst, int E) {
  int i = blockIdx.x * blockDim.x + threadIdx.x;
  int stride = gridDim.x * blockDim.x;
  for (; i < E; i += stride) {
    atomicAdd(&cnt_src[src[i]], 1);
    atomicAdd(&cnt_dst[dst[i]], 1);
  }
}

// ---------------- scan: row_ptr/cursor + dinv ----------------
__global__ __launch_bounds__(256) void scan_kernel(
    const int* __restrict__ cnt_src, const int* __restrict__ cnt_dst,
    float* __restrict__ dinv, int* __restrict__ row_ptr, int* __restrict__ cursor, int N) {
  __shared__ int part[256];
  int t = threadIdx.x;
  int chunk = (N + 255) / 256;
  int base = t * chunk;
  int sum = 0;
  for (int i = 0; i < chunk; ++i) {
    int idx = base + i;
    if (idx < N) sum += cnt_dst[idx];
  }
  part[t] = sum;
  __syncthreads();
  if (t == 0) {
    int run = 0;
    for (int i = 0; i < 256; ++i) { int v = part[i]; part[i] = run; run += v; }
  }
  __syncthreads();
  int run = part[t];
  for (int i = 0; i < chunk; ++i) {
    int idx = base + i;
    if (idx < N) {
      int v = cnt_dst[idx];
      row_ptr[idx] = run; cursor[idx] = run; run += v;
      int dg = cnt_src[idx];
      dinv[idx] = dg > 0 ? rsqrtf((float)dg) : 0.f;
    }
  }
  if (t == 255) row_ptr[N] = run;
}

// ---------------- CSR scatter ----------------
__global__ void scatter_kernel(const int* __restrict__ src, const int* __restrict__ dst,
                               int* __restrict__ cursor, int* __restrict__ csr_src, int E) {
  int i = blockIdx.x * blockDim.x + threadIdx.x;
  int stride = gridDim.x * blockDim.x;
  for (; i < E; i += stride) {
    int pos = atomicAdd(&cursor[dst[i]], 1);
    csr_src[pos] = src[i];
  }
}

// ---------------- GCN aggregation (block per dst node) ----------------
__global__ __launch_bounds__(128) void agg_kernel(
    const float* __restrict__ feats, const float* __restrict__ dinv,
    const int* __restrict__ row_ptr, const int* __restrict__ csr_src,
    float* __restrict__ out) {
  __shared__ int idx[128];
  __shared__ float dv[128];
  int n = blockIdx.x, f = threadIdx.x;
  int beg = row_ptr[n], end = row_ptr[n + 1];
  float acc = 0.f;
  for (int c = beg; c < end; c += 128) {
    int j = c + f;
    if (j < end) { int s = csr_src[j]; idx[f] = s; dv[f] = dinv[s]; }
    __syncthreads();
    int cnt = min(128, end - c);
    for (int u = 0; u < cnt; ++u)
      acc += feats[idx[u] * D + f] * dv[u];
    __syncthreads();
  }
  out[n * D + f] = acc * dinv[n];
}

// ---------------- generic fp32 GEMM: C = act(A1@W1^T [+ A2@W2^T] + b1 [+ b2] [+ R]) ----------------
__global__ __launch_bounds__(256) void gemm128_kernel(
    const float* __restrict__ A1, const float* __restrict__ W1, const float* __restrict__ b1,
    const float* __restrict__ A2, const float* __restrict__ W2, const float* __restrict__ b2,
    const float* __restrict__ Rres, float* __restrict__ C, int act) {
  __shared__ float As[32][36];
  __shared__ float Ws[32][132];
  const int t = threadIdx.x;
  const int m0 = blockIdx.x * 32;
  const int tr = t >> 5, tc = t & 31;
  float acc[4][4] = {};
  for (int pair = 0; pair < 2; ++pair) {
    const float* A = pair ? A2 : A1;
    const float* W = pair ? W2 : W1;
    if (A == nullptr) break;
    for (int kc = 0; kc < 128; kc += 32) {
      __syncthreads();
      {
        int r = t >> 3, kq = t & 7;
        float4 v = ld4(&A[(m0 + r) * D + kc + kq * 4]);
        As[kq * 4 + 0][r] = v.x; As[kq * 4 + 1][r] = v.y;
        As[kq * 4 + 2][r] = v.z; As[kq * 4 + 3][r] = v.w;
      }
      for (int i = 0; i < 4; ++i) {
        int id = t + i * 256; int n = id >> 3, kq = id & 7;
        float4 v = ld4(&W[n * D + kc + kq * 4]);
        Ws[kq * 4 + 0][n] = v.x; Ws[kq * 4 + 1][n] = v.y;
        Ws[kq * 4 + 2][n] = v.z; Ws[kq * 4 + 3][n] = v.w;
      }
      __syncthreads();
#pragma unroll
      for (int kd = 0; kd < 32; ++kd) {
        float4 a = *(const float4*)&As[kd][tr * 4];
        float4 w = *(const float4*)&Ws[kd][tc * 4];
        float aa[4] = {a.x, a.y, a.z, a.w};
        float ww[4] = {w.x, w.y, w.z, w.w};
#pragma unroll
        for (int i = 0; i < 4; ++i)
#pragma unroll
          for (int j = 0; j < 4; ++j) acc[i][j] += aa[i] * ww[j];
      }
    }
  }
  float bias[4] = {0.f, 0.f, 0.f, 0.f};
  if (b1) { float4 bb = ld4(&b1[tc * 4]); bias[0] += bb.x; bias[1] += bb.y; bias[2] += bb.z; bias[3] += bb.w; }
  if (b2) { float4 bb = ld4(&b2[tc * 4]); bias[0] += bb.x; bias[1] += bb.y; bias[2] += bb.z; bias[3] += bb.w; }
#pragma unroll
  for (int i = 0; i < 4; ++i) {
    int m = m0 + tr * 4 + i;
    float v[4];
#pragma unroll
    for (int j = 0; j < 4; ++j) v[j] = acc[i][j] + bias[j];
    if (Rres) {
      float4 rr = ld4(&Rres[m * D + tc * 4]);
      v[0] += rr.x; v[1] += rr.y; v[2] += rr.z; v[3] += rr.w;
    }
    if (act) {
#pragma unroll
      for (int j = 0; j < 4; ++j) v[j] = fmaxf(v[j], 0.f);
    }
    float4 ov = {v[0], v[1], v[2], v[3]};
    *(float4*)&C[m * D + tc * 4] = ov;
  }
}

// ---------------- MFMA flash attention (bf16 compute, fp32 accumulate) ----------------
// block = 256 (4 waves), wave w = head w; 32 q-rows per block; 32-key chunks.
// Layouts (16x16x32 bf16 MFMA, verified m89/m91):
//   A-frag: element [m=lane&15][k=quad*8+j]; B-frag: [n=lane&15][k=quad*8+j]; C: col=lane&15,row=quad*4+reg
#define FA_KS 136   // Ks stride (bf16 elems), 272B: b128-aligned, 2-way banks (free)
#define FA_VS 40    // Vt stride, 80B: b128-aligned; kq XOR-swizzle for writes
#define FA_PS 36    // Ps stride, 72B: b64 reads, conflict-free
__global__ __launch_bounds__(256) void flash_mfma_kernel(
    const float* __restrict__ Q, const float* __restrict__ Kb, const float* __restrict__ Vb,
    float* __restrict__ O, int Slen) {
  __shared__ short Ks[32 * FA_KS];        // [key][dim]
  __shared__ short Vt[128 * FA_VS];       // [dim][key grp swizzled]
  __shared__ short Ps[4][32 * FA_PS];     // per head [row][key]
  const int t = threadIdx.x;
  const int h = t >> 6;
  const int lane = t & 63;
  const int quad = lane >> 4;
  const int r16 = lane & 15;
  const int n0 = blockIdx.x * 32;
  const float scale = 0.17677669529663687f; // 1/sqrt(32), folded into Q

  // Q fragments: A-layout, direct from global (reused over all 64 chunks)
  bf16x8 aq[2];
#pragma unroll
  for (int rt = 0; rt < 2; ++rt) {
    const float* qp = &Q[(size_t)(n0 + rt * 16 + r16) * D + h * 32 + quad * 8];
    float4 q0 = ld4(qp), q1 = ld4(qp + 4);
    aq[rt][0] = f2bf(q0.x * scale); aq[rt][1] = f2bf(q0.y * scale);
    aq[rt][2] = f2bf(q0.z * scale); aq[rt][3] = f2bf(q0.w * scale);
    aq[rt][4] = f2bf(q1.x * scale); aq[rt][5] = f2bf(q1.y * scale);
    aq[rt][6] = f2bf(q1.z * scale); aq[rt][7] = f2bf(q1.w * scale);
  }
  f32x4 o[2][2];
  float m_i[2][4], l_i[2][4];
#pragma unroll
  for (int rt = 0; rt < 2; ++rt) {
#pragma unroll
    for (int nt = 0; nt < 2; ++nt) { f32x4 z = {0.f, 0.f, 0.f, 0.f}; o[rt][nt] = z; }
#pragma unroll
    for (int g = 0; g < 4; ++g) { m_i[rt][g] = -1e30f; l_i[rt][g] = 0.f; }
  }

  for (int c = 0; c < Slen; c += 32) {
    __syncthreads();   // protect Ks/Vt from previous chunk's readers
    // stage K chunk: [key][dim] bf16
#pragma unroll
    for (int i = 0; i < 4; ++i) {
      int id = t + i * 256;              // 1024 float4 groups
      int key = id >> 5, col = (id & 31) * 4;
      float4 v = ld4(&Kb[(size_t)(c + key) * D + col]);
      bf16x4 w = {f2bf(v.x), f2bf(v.y), f2bf(v.z), f2bf(v.w)};
      *(bf16x4*)&Ks[key * FA_KS + col] = w;
    }
    // stage V transposed: Vt[dim][key], 4-key groups XOR-swizzled by (dim>>3)&3
#pragma unroll
    for (int i = 0; i < 4; ++i) {
      int id = t + i * 256;              // 1024 b64 groups
      int dim = id & 127, kq = id >> 7;  // kq 0..7
      int kqs = kq ^ (((dim >> 3) & 3) << 1);
      const float* vp = &Vb[(size_t)(c + kq * 4) * D + dim];
      bf16x4 w = {f2bf(vp[0]), f2bf(vp[D]), f2bf(vp[2 * D]), f2bf(vp[3 * D])};
      *(bf16x4*)&Vt[dim * FA_VS + kqs * 4] = w;
    }
    __syncthreads();
    // QK^T: 2 row-tiles x 2 key-tiles, K=32 (one MFMA step)
    f32x4 s[2][2];
#pragma unroll
    for (int kt = 0; kt < 2; ++kt) {
      bf16x8 bk = *(bf16x8*)&Ks[(kt * 16 + r16) * FA_KS + h * 32 + quad * 8];
      f32x4 z = {0.f, 0.f, 0.f, 0.f};
#pragma unroll
      for (int rt = 0; rt < 2; ++rt) {
        s[rt][kt] = __builtin_amdgcn_mfma_f32_16x16x32_bf16(aq[rt], bk, z, 0, 0, 0);
      }
    }
    // online softmax (row = quad*4+reg lives in-register, duplicated across 16 lanes)
#pragma unroll
    for (int rt = 0; rt < 2; ++rt) {
      float al[4];
#pragma unroll
      for (int g = 0; g < 4; ++g) {
        float v = fmaxf(s[rt][0][g], s[rt][1][g]);
        v = fmaxf(v, __shfl_xor(v, 1)); v = fmaxf(v, __shfl_xor(v, 2));
        v = fmaxf(v, __shfl_xor(v, 4)); v = fmaxf(v, __shfl_xor(v, 8));
        float mn = fmaxf(m_i[rt][g], v);
        al[g] = __expf(m_i[rt][g] - mn);
        m_i[rt][g] = mn;
        float ps = 0.f;
#pragma unroll
        for (int kt = 0; kt < 2; ++kt) {
          float p = __expf(s[rt][kt][g] - mn);
          Ps[h][(rt * 16 + quad * 4 + g) * FA_PS + kt * 16 + r16] = f2bf(p);
          ps += p;
        }
        ps += __shfl_xor(ps, 1); ps += __shfl_xor(ps, 2);
        ps += __shfl_xor(ps, 4); ps += __shfl_xor(ps, 8);
        l_i[rt][g] = l_i[rt][g] * al[g] + ps;
      }
#pragma unroll
      for (int nt = 0; nt < 2; ++nt)
#pragma unroll
        for (int g = 0; g < 4; ++g) o[rt][nt][g] *= al[g];
    }
    // PV: P (A-layout via LDS round-trip) x Vt (B-layout)
#pragma unroll
    for (int rt = 0; rt < 2; ++rt) {
      bf16x4 p0 = *(bf16x4*)&Ps[h][(rt * 16 + r16) * FA_PS + quad * 8];
      bf16x4 p1 = *(bf16x4*)&Ps[h][(rt * 16 + r16) * FA_PS + quad * 8 + 4];
      bf16x8 ap = __builtin_shufflevector(p0, p1, 0, 1, 2, 3, 4, 5, 6, 7);
#pragma unroll
      for (int nt = 0; nt < 2; ++nt) {
        int dim = h * 32 + nt * 16 + r16;
        int xr = ((dim >> 3) & 3) << 1;
        bf16x8 bv = *(bf16x8*)&Vt[dim * FA_VS + ((2 * quad) ^ xr) * 4];
        o[rt][nt] = __builtin_amdgcn_mfma_f32_16x16x32_bf16(ap, bv, o[rt][nt], 0, 0, 0);
      }
    }
  }
  // epilogue: O = o / l
#pragma unroll
  for (int rt = 0; rt < 2; ++rt)
#pragma unroll
    for (int g = 0; g < 4; ++g) {
      float linv = 1.f / l_i[rt][g];
      int row = n0 + rt * 16 + quad * 4 + g;
#pragma unroll
      for (int nt = 0; nt < 2; ++nt)
        O[(size_t)row * D + h * 32 + nt * 16 + r16] = o[rt][nt][g] * linv;
    }
}

// ---------------- LayerNorm + L2 normalize (1 wave per row) ----------------
__global__ __launch_bounds__(64) void ln_l2_kernel(
    const float* __restrict__ X, const float* __restrict__ g, const float* __restrict__ b,
    float* __restrict__ out) {
  int n = blockIdx.x, t = threadIdx.x;
  float2 v = *(const float2*)&X[n * D + t * 2];
  float s = v.x + v.y;
  for (int off = 32; off; off >>= 1) s += __shfl_xor(s, off);
  float mu = s * (1.f / 128.f);
  float dx = v.x - mu, dy = v.y - mu;
  float q = dx * dx + dy * dy;
  for (int off = 32; off; off >>= 1) q += __shfl_xor(q, off);
  float rs = rsqrtf(q * (1.f / 128.f) + 1e-5f);
  float2 gg = *(const float2*)&g[t * 2];
  float2 bb = *(const float2*)&b[t * 2];
  float yx = dx * rs * gg.x + bb.x;
  float yy = dy * rs * gg.y + bb.y;
  float nn = yx * yx + yy * yy;
  for (int off = 32; off; off >>= 1) nn += __shfl_xor(nn, off);
  float inv = 1.f / fmaxf(sqrtf(nn), 1e-12f);
  float2 ov = {yx * inv, yy * inv};
  *(float2*)&out[n * D + t * 2] = ov;
}

// ---------------- MLP layer 2 + sigmoid ----------------
__global__ __launch_bounds__(256) void mlp2_kernel(
    const float* __restrict__ H, const float* __restrict__ w2, float* __restrict__ p, int M) {
  int row = blockIdx.x * 4 + (threadIdx.x >> 6);
  int lane = threadIdx.x & 63;
  if (row >= M) return;
  float2 h2 = *(const float2*)&H[row * D + lane * 2];
  float2 w = *(const float2*)&w2[lane * 2];
  float s = h2.x * w.x + h2.y * w.y;
  for (int off = 32; off; off >>= 1) s += __shfl_xor(s, off);
  if (lane == 0) p[row] = 1.f / (1.f + __expf(-s));
}

// ---------------- edge prediction ----------------
__global__ void pred_kernel(const float* __restrict__ p, const int* __restrict__ eli,
                            float* __restrict__ out, int K) {
  int i = blockIdx.x * blockDim.x + threadIdx.x;
  if (i < K) out[i] = p[eli[i]] * p[eli[K + i]];
}

extern "C" void kernel_launch(void* const* d_in, const int* in_sizes, int n_in,
                              void* d_out, int out_size, void* d_ws, size_t ws_size,
                              hipStream_t stream) {
  const float* x       = (const float*)d_in[0];
  const float* seq     = (const float*)d_in[1];
  const int* src       = (const int*)d_in[2];
  const int* dst       = (const int*)d_in[3];
  const int* eli       = (const int*)d_in[4];
  const float* skip_w0 = (const float*)d_in[5];
  const float* skip_b0 = (const float*)d_in[6];
  const float* msg_w0  = (const float*)d_in[7];
  const float* msg_b0  = (const float*)d_in[8];
  const float* skip_w1 = (const float*)d_in[9];
  const float* skip_b1 = (const float*)d_in[10];
  const float* msg_w1  = (const float*)d_in[11];
  const float* msg_b1  = (const float*)d_in[12];
  const float* ipw     = (const float*)d_in[13];
  const float* ipb     = (const float*)d_in[14];
  const float* opw     = (const float*)d_in[15];
  const float* opb     = (const float*)d_in[16];
  const float* ln_g    = (const float*)d_in[17];
  const float* ln_b    = (const float*)d_in[18];
  const float* w1      = (const float*)d_in[19];
  const float* w2      = (const float*)d_in[20];

  const int N  = in_sizes[0] / D;   // 8192
  const int S  = in_sizes[1] / D;   // 2048
  const int E  = in_sizes[2];       // 524288
  const int Kp = in_sizes[4] / 2;   // 100000

  float* ws   = (float*)d_ws;
  float* B0   = ws;
  float* B1   = B0 + (size_t)N * D;
  float* B2   = B1 + (size_t)N * D;
  float* B3   = B2 + (size_t)N * D;
  float* KB   = B3 + (size_t)N * D;
  float* VB   = KB + (size_t)S * D;
  float* dinv = VB + (size_t)S * D;
  float* pbuf = dinv + N;
  int* cnt_src = (int*)(pbuf + N);
  int* cnt_dst = cnt_src + N;
  int* row_ptr = cnt_dst + N;
  int* cursor  = row_ptr + (N + 1);
  int* csr_src = cursor + N;

  float* pred_out = (float*)d_out;
  float* emb_out  = pred_out + Kp;

  hipMemsetAsync(cnt_src, 0, 2 * (size_t)N * sizeof(int), stream);
  count_kernel<<<512, 256, 0, stream>>>(src, dst, cnt_src, cnt_dst, E);
  scan_kernel<<<1, 256, 0, stream>>>(cnt_src, cnt_dst, dinv, row_ptr, cursor, N);
  scatter_kernel<<<512, 256, 0, stream>>>(src, dst, cursor, csr_src, E);

  agg_kernel<<<N, 128, 0, stream>>>(x, dinv, row_ptr, csr_src, B0);
  gemm128_kernel<<<N / 32, 256, 0, stream>>>(B0, msg_w0, msg_b0, x, skip_w0, skip_b0, nullptr, B1, 0);
  agg_kernel<<<N, 128, 0, stream>>>(B1, dinv, row_ptr, csr_src, B0);
  gemm128_kernel<<<N / 32, 256, 0, stream>>>(B0, msg_w1, msg_b1, B1, skip_w1, skip_b1, nullptr, B2, 0);

  gemm128_kernel<<<N / 32, 256, 0, stream>>>(B2, ipw, ipb, nullptr, nullptr, nullptr, nullptr, B3, 0);
  gemm128_kernel<<<S / 32, 256, 0, stream>>>(seq, ipw + D * D, ipb + D, nullptr, nullptr, nullptr, nullptr, KB, 0);
  gemm128_kernel<<<S / 32, 256, 0, stream>>>(seq, ipw + 2 * D * D, ipb + 2 * D, nullptr, nullptr, nullptr, nullptr, VB, 0);
  flash_mfma_kernel<<<N / 32, 256, 0, stream>>>(B3, KB, VB, B0, S);
  gemm128_kernel<<<N / 32, 256, 0, stream>>>(B0, opw, opb, nullptr, nullptr, nullptr, B2, B1, 0);
  ln_l2_kernel<<<N, 64, 0, stream>>>(B1, ln_g, ln_b, emb_out);
  gemm128_kernel<<<N / 32, 256, 0, stream>>>(emb_out, w1, nullptr, nullptr, nullptr, nullptr, nullptr, B3, 1);
  mlp2_kernel<<<N / 4, 256, 0, stream>>>(B3, w2, pbuf, N);
  pred_kernel<<<(Kp + 255) / 256, 256, 0, stream>>>(pbuf, eli, pred_out, Kp);
}

// Round 3
// 403.846 us; speedup vs baseline: 1.4921x; 1.4921x over previous
//
#include <hip/hip_runtime.h>
#include <math.h>

#define D 128

typedef short bf16x4 __attribute__((ext_vector_type(4)));
typedef short bf16x8 __attribute__((ext_vector_type(8)));
typedef float f32x4 __attribute__((ext_vector_type(4)));

__device__ __forceinline__ float4 ld4(const float* p) { return *(const float4*)p; }

__device__ __forceinline__ short f2bf(float f) {
  unsigned u = __float_as_uint(f);
  u += 0x7FFF + ((u >> 16) & 1);
  return (short)(u >> 16);
}

// ---------------- degree counting ----------------
__global__ void count_kernel(const int* __restrict__ src, const int* __restrict__ dst,
                             int* __restrict__ cnt_src, int* __restrict__ cnt_dst, int E) {
  int i = blockIdx.x * blockDim.x + threadIdx.x;
  int stride = gridDim.x * blockDim.x;
  for (; i < E; i += stride) {
    atomicAdd(&cnt_src[src[i]], 1);
    atomicAdd(&cnt_dst[dst[i]], 1);
  }
}

// ---------------- scan: row_ptr/cursor + dinv ----------------
__global__ __launch_bounds__(256) void scan_kernel(
    const int* __restrict__ cnt_src, const int* __restrict__ cnt_dst,
    float* __restrict__ dinv, int* __restrict__ row_ptr, int* __restrict__ cursor, int N) {
  __shared__ int part[256];
  int t = threadIdx.x;
  int chunk = (N + 255) / 256;
  int base = t * chunk;
  int sum = 0;
  for (int i = 0; i < chunk; ++i) {
    int idx = base + i;
    if (idx < N) sum += cnt_dst[idx];
  }
  part[t] = sum;
  __syncthreads();
  if (t == 0) {
    int run = 0;
    for (int i = 0; i < 256; ++i) { int v = part[i]; part[i] = run; run += v; }
  }
  __syncthreads();
  int run = part[t];
  for (int i = 0; i < chunk; ++i) {
    int idx = base + i;
    if (idx < N) {
      int v = cnt_dst[idx];
      row_ptr[idx] = run; cursor[idx] = run; run += v;
      int dg = cnt_src[idx];
      dinv[idx] = dg > 0 ? rsqrtf((float)dg) : 0.f;
    }
  }
  if (t == 255) row_ptr[N] = run;
}

// ---------------- CSR scatter ----------------
__global__ void scatter_kernel(const int* __restrict__ src, const int* __restrict__ dst,
                               int* __restrict__ cursor, int* __restrict__ csr_src, int E) {
  int i = blockIdx.x * blockDim.x + threadIdx.x;
  int stride = gridDim.x * blockDim.x;
  for (; i < E; i += stride) {
    int pos = atomicAdd(&cursor[dst[i]], 1);
    csr_src[pos] = src[i];
  }
}

// ---------------- GCN aggregation (block per dst node, float4 lanes) ----------------
__global__ __launch_bounds__(128) void agg_kernel(
    const float* __restrict__ feats, const float* __restrict__ dinv,
    const int* __restrict__ row_ptr, const int* __restrict__ csr_src,
    float* __restrict__ out) {
  __shared__ int idx[128];
  __shared__ float dv[128];
  __shared__ float4 red[128];
  int n = blockIdx.x, t = threadIdx.x;
  int lane = t & 31, grp = t >> 5;
  int beg = row_ptr[n], end = row_ptr[n + 1];
  float4 acc = {0.f, 0.f, 0.f, 0.f};
  for (int c = beg; c < end; c += 128) {
    int j = c + t;
    if (j < end) { int s = csr_src[j]; idx[t] = s; dv[t] = dinv[s]; }
    __syncthreads();
    int cnt = min(128, end - c);
    for (int e = grp; e < cnt; e += 4) {
      float4 v = ld4(&feats[(size_t)idx[e] * D + lane * 4]);
      float w = dv[e];
      acc.x += v.x * w; acc.y += v.y * w; acc.z += v.z * w; acc.w += v.w * w;
    }
    __syncthreads();
  }
  red[t] = acc;
  __syncthreads();
  if (t < 32) {
    float4 a = red[t], b = red[32 + t], c2 = red[64 + t], d2 = red[96 + t];
    float w = dinv[n];
    float4 o2 = {(a.x + b.x + c2.x + d2.x) * w, (a.y + b.y + c2.y + d2.y) * w,
                 (a.z + b.z + c2.z + d2.z) * w, (a.w + b.w + c2.w + d2.w) * w};
    *(float4*)&out[(size_t)n * D + t * 4] = o2;
  }
}

// ---------------- generic fp32 GEMM: C = act(A1@W1^T [+ A2@W2^T] + b1 [+ b2] [+ R]) ----------------
__global__ __launch_bounds__(256) void gemm128_kernel(
    const float* __restrict__ A1, const float* __restrict__ W1, const float* __restrict__ b1,
    const float* __restrict__ A2, const float* __restrict__ W2, const float* __restrict__ b2,
    const float* __restrict__ Rres, float* __restrict__ C, int act) {
  __shared__ float As[32][36];
  __shared__ float Ws[32][132];
  const int t = threadIdx.x;
  const int m0 = blockIdx.x * 32;
  const int tr = t >> 5, tc = t & 31;
  float acc[4][4] = {};
  for (int pair = 0; pair < 2; ++pair) {
    const float* A = pair ? A2 : A1;
    const float* W = pair ? W2 : W1;
    if (A == nullptr) break;
    for (int kc = 0; kc < 128; kc += 32) {
      __syncthreads();
      {
        int r = t >> 3, kq = t & 7;
        float4 v = ld4(&A[(m0 + r) * D + kc + kq * 4]);
        As[kq * 4 + 0][r] = v.x; As[kq * 4 + 1][r] = v.y;
        As[kq * 4 + 2][r] = v.z; As[kq * 4 + 3][r] = v.w;
      }
      for (int i = 0; i < 4; ++i) {
        int id = t + i * 256; int n = id >> 3, kq = id & 7;
        float4 v = ld4(&W[n * D + kc + kq * 4]);
        Ws[kq * 4 + 0][n] = v.x; Ws[kq * 4 + 1][n] = v.y;
        Ws[kq * 4 + 2][n] = v.z; Ws[kq * 4 + 3][n] = v.w;
      }
      __syncthreads();
#pragma unroll
      for (int kd = 0; kd < 32; ++kd) {
        float4 a = *(const float4*)&As[kd][tr * 4];
        float4 w = *(const float4*)&Ws[kd][tc * 4];
        float aa[4] = {a.x, a.y, a.z, a.w};
        float ww[4] = {w.x, w.y, w.z, w.w};
#pragma unroll
        for (int i = 0; i < 4; ++i)
#pragma unroll
          for (int j = 0; j < 4; ++j) acc[i][j] += aa[i] * ww[j];
      }
    }
  }
  float bias[4] = {0.f, 0.f, 0.f, 0.f};
  if (b1) { float4 bb = ld4(&b1[tc * 4]); bias[0] += bb.x; bias[1] += bb.y; bias[2] += bb.z; bias[3] += bb.w; }
  if (b2) { float4 bb = ld4(&b2[tc * 4]); bias[0] += bb.x; bias[1] += bb.y; bias[2] += bb.z; bias[3] += bb.w; }
#pragma unroll
  for (int i = 0; i < 4; ++i) {
    int m = m0 + tr * 4 + i;
    float v[4];
#pragma unroll
    for (int j = 0; j < 4; ++j) v[j] = acc[i][j] + bias[j];
    if (Rres) {
      float4 rr = ld4(&Rres[m * D + tc * 4]);
      v[0] += rr.x; v[1] += rr.y; v[2] += rr.z; v[3] += rr.w;
    }
    if (act) {
#pragma unroll
      for (int j = 0; j < 4; ++j) v[j] = fmaxf(v[j], 0.f);
    }
    float4 ov = {v[0], v[1], v[2], v[3]};
    *(float4*)&C[m * D + tc * 4] = ov;
  }
}

// ---------------- K/V prep: fp32 -> bf16, V transposed, per-head max |k|^2 ----------------
// grid = S/32 blocks x 256 threads
__global__ __launch_bounds__(256) void kv_prep_kernel(
    const float* __restrict__ KB, const float* __restrict__ VB,
    short* __restrict__ Kbf, short* __restrict__ Vt, int* __restrict__ MkhI, int S) {
  __shared__ short VtS[128 * 40];
  __shared__ float kn[128];   // [key 0..31][head 0..3]
  const int t = threadIdx.x;
  const int s0 = blockIdx.x * 32;
  if (t < 128) kn[t] = 0.f;
  __syncthreads();
#pragma unroll
  for (int i = 0; i < 4; ++i) {
    int id = t + i * 256;
    int key = id >> 5, d4 = (id & 31) * 4;
    float4 kv = ld4(&KB[(size_t)(s0 + key) * D + d4]);
    bf16x4 kw = {f2bf(kv.x), f2bf(kv.y), f2bf(kv.z), f2bf(kv.w)};
    *(bf16x4*)&Kbf[(size_t)(s0 + key) * D + d4] = kw;
    float ss = kv.x * kv.x + kv.y * kv.y + kv.z * kv.z + kv.w * kv.w;
    atomicAdd(&kn[key * 4 + (d4 >> 5)], ss);
    float4 vv = ld4(&VB[(size_t)(s0 + key) * D + d4]);
    VtS[(d4 + 0) * 40 + key] = f2bf(vv.x);
    VtS[(d4 + 1) * 40 + key] = f2bf(vv.y);
    VtS[(d4 + 2) * 40 + key] = f2bf(vv.z);
    VtS[(d4 + 3) * 40 + key] = f2bf(vv.w);
  }
  __syncthreads();
  if (t < 128) {
    int key = t >> 2, h = t & 3;
    atomicMax(&MkhI[h], __float_as_int(kn[key * 4 + h]));
  }
  int dim = t >> 1, half = t & 1;
  bf16x8 v0 = *(bf16x8*)&VtS[dim * 40 + half * 16];
  bf16x8 v1 = *(bf16x8*)&VtS[dim * 40 + half * 16 + 8];
  *(bf16x8*)&Vt[(size_t)dim * S + s0 + half * 16] = v0;
  *(bf16x8*)&Vt[(size_t)dim * S + s0 + half * 16 + 8] = v1;
}

// ---------------- Q prep: scale by 1/sqrt(32), bf16, row-head shift bound ----------------
// grid = N/16 blocks x 256 threads; 16 lanes per row
__global__ __launch_bounds__(256) void q_prep_kernel(
    const float* __restrict__ Qf, const int* __restrict__ MkhI,
    short* __restrict__ Qbf, float* __restrict__ mrow, int N) {
  const int t = threadIdx.x;
  const int r = blockIdx.x * 16 + (t >> 4);
  const int l16 = t & 15;
  const float s32 = 0.17677669529663687f; // 1/sqrt(32)
  const float* qp = &Qf[(size_t)r * D + l16 * 8];
  float4 a = ld4(qp), b = ld4(qp + 4);
  a.x *= s32; a.y *= s32; a.z *= s32; a.w *= s32;
  b.x *= s32; b.y *= s32; b.z *= s32; b.w *= s32;
  bf16x8 w = {f2bf(a.x), f2bf(a.y), f2bf(a.z), f2bf(a.w),
              f2bf(b.x), f2bf(b.y), f2bf(b.z), f2bf(b.w)};
  *(bf16x8*)&Qbf[(size_t)r * D + l16 * 8] = w;
  float ss = a.x * a.x + a.y * a.y + a.z * a.z + a.w * a.w +
             b.x * b.x + b.y * b.y + b.z * b.z + b.w * b.w;
  ss += __shfl_xor(ss, 1);
  ss += __shfl_xor(ss, 2);
  if ((l16 & 3) == 0) {
    int h = l16 >> 2;
    float mk = __int_as_float(MkhI[h]);          // max |k_h|^2 (>=0)
    mrow[h * N + r] = sqrtf(ss) * sqrtf(fmaxf(mk, 0.f));
  }
}

// ---------------- MFMA flash attention, fixed-shift softmax, split-S ----------------
// block = 64 (one wave); grid = (N/32, NH=4, SPLITS=4)
__global__ __launch_bounds__(64, 4) void flash_kernel(
    const short* __restrict__ Qbf, const short* __restrict__ Kbf, const short* __restrict__ Vt,
    const float* __restrict__ mrow, float* __restrict__ O, float* __restrict__ lbuf,
    int N, int S) {
  __shared__ short Ps[32 * 72];
  const int lane = threadIdx.x;
  const int quad = lane >> 4, r16 = lane & 15;
  const int n0 = blockIdx.x * 32;
  const int h = blockIdx.y;
  const int sp = blockIdx.z;

  bf16x8 aq[2];
  aq[0] = *(const bf16x8*)&Qbf[(size_t)(n0 + r16) * D + h * 32 + quad * 8];
  aq[1] = *(const bf16x8*)&Qbf[(size_t)(n0 + 16 + r16) * D + h * 32 + quad * 8];

  float msh[2][4];
#pragma unroll
  for (int rt = 0; rt < 2; ++rt)
#pragma unroll
    for (int g = 0; g < 4; ++g)
      msh[rt][g] = fminf(mrow[h * N + n0 + rt * 16 + quad * 4 + g], 40.f);

  f32x4 o[2][2], lac[2];
  f32x4 zz = {0.f, 0.f, 0.f, 0.f};
  o[0][0] = zz; o[0][1] = zz; o[1][0] = zz; o[1][1] = zz;
  lac[0] = zz; lac[1] = zz;
  bf16x8 ones = {(short)0x3F80, (short)0x3F80, (short)0x3F80, (short)0x3F80,
                 (short)0x3F80, (short)0x3F80, (short)0x3F80, (short)0x3F80};

  const int span = S >> 2;          // keys per split
  const int c0 = sp * span;
  for (int c = c0; c < c0 + span; c += 64) {
    f32x4 s[2][4];
#pragma unroll
    for (int kt = 0; kt < 4; ++kt) {
      bf16x8 bk = *(const bf16x8*)&Kbf[(size_t)(c + kt * 16 + r16) * D + h * 32 + quad * 8];
      f32x4 z = {0.f, 0.f, 0.f, 0.f};
      s[0][kt] = __builtin_amdgcn_mfma_f32_16x16x32_bf16(aq[0], bk, z, 0, 0, 0);
      s[1][kt] = __builtin_amdgcn_mfma_f32_16x16x32_bf16(aq[1], bk, z, 0, 0, 0);
    }
#pragma unroll
    for (int rt = 0; rt < 2; ++rt)
#pragma unroll
      for (int kt = 0; kt < 4; ++kt)
#pragma unroll
        for (int g = 0; g < 4; ++g) {
          float p = __expf(s[rt][kt][g] - msh[rt][g]);
          Ps[(rt * 16 + quad * 4 + g) * 72 + kt * 16 + r16] = f2bf(p);
        }
    // same-wave LDS round-trip: compiler inserts lgkmcnt waits, no barrier needed
#pragma unroll
    for (int rt = 0; rt < 2; ++rt)
#pragma unroll
      for (int kc = 0; kc < 2; ++kc) {
        bf16x8 ap = *(bf16x8*)&Ps[(rt * 16 + r16) * 72 + kc * 32 + quad * 8];
        lac[rt] = __builtin_amdgcn_mfma_f32_16x16x32_bf16(ap, ones, lac[rt], 0, 0, 0);
#pragma unroll
        for (int nt = 0; nt < 2; ++nt) {
          bf16x8 bv = *(const bf16x8*)&Vt[(size_t)(h * 32 + nt * 16 + r16) * S + c + kc * 32 + quad * 8];
          o[rt][nt] = __builtin_amdgcn_mfma_f32_16x16x32_bf16(ap, bv, o[rt][nt], 0, 0, 0);
        }
      }
  }
#pragma unroll
  for (int rt = 0; rt < 2; ++rt)
#pragma unroll
    for (int g = 0; g < 4; ++g) {
      int row = n0 + rt * 16 + quad * 4 + g;
#pragma unroll
      for (int nt = 0; nt < 2; ++nt)
        atomicAdd(&O[(size_t)row * D + h * 32 + nt * 16 + r16], o[rt][nt][g]);
      if (r16 == 0) atomicAdd(&lbuf[h * N + row], lac[rt][g]);
    }
}

// ---------------- attention normalize: O /= l ----------------
__global__ __launch_bounds__(256) void attn_norm_kernel(
    float* __restrict__ O, const float* __restrict__ lbuf, int N) {
  int tid = blockIdx.x * 256 + threadIdx.x;   // N*32 threads
  int row = tid >> 5, c4 = (tid & 31) * 4, h = c4 >> 5;
  float inv = 1.f / lbuf[h * N + row];
  float4 v = ld4(&O[(size_t)row * D + c4]);
  v.x *= inv; v.y *= inv; v.z *= inv; v.w *= inv;
  *(float4*)&O[(size_t)row * D + c4] = v;
}

// ---------------- LayerNorm + L2 normalize (1 wave per row) ----------------
__global__ __launch_bounds__(64) void ln_l2_kernel(
    const float* __restrict__ X, const float* __restrict__ g, const float* __restrict__ b,
    float* __restrict__ out) {
  int n = blockIdx.x, t = threadIdx.x;
  float2 v = *(const float2*)&X[n * D + t * 2];
  float s = v.x + v.y;
  for (int off = 32; off; off >>= 1) s += __shfl_xor(s, off);
  float mu = s * (1.f / 128.f);
  float dx = v.x - mu, dy = v.y - mu;
  float q = dx * dx + dy * dy;
  for (int off = 32; off; off >>= 1) q += __shfl_xor(q, off);
  float rs = rsqrtf(q * (1.f / 128.f) + 1e-5f);
  float2 gg = *(const float2*)&g[t * 2];
  float2 bb = *(const float2*)&b[t * 2];
  float yx = dx * rs * gg.x + bb.x;
  float yy = dy * rs * gg.y + bb.y;
  float nn = yx * yx + yy * yy;
  for (int off = 32; off; off >>= 1) nn += __shfl_xor(nn, off);
  float inv = 1.f / fmaxf(sqrtf(nn), 1e-12f);
  float2 ov = {yx * inv, yy * inv};
  *(float2*)&out[n * D + t * 2] = ov;
}

// ---------------- MLP layer 2 + sigmoid ----------------
__global__ __launch_bounds__(256) void mlp2_kernel(
    const float* __restrict__ H, const float* __restrict__ w2, float* __restrict__ p, int M) {
  int row = blockIdx.x * 4 + (threadIdx.x >> 6);
  int lane = threadIdx.x & 63;
  if (row >= M) return;
  float2 h2 = *(const float2*)&H[row * D + lane * 2];
  float2 w = *(const float2*)&w2[lane * 2];
  float s = h2.x * w.x + h2.y * w.y;
  for (int off = 32; off; off >>= 1) s += __shfl_xor(s, off);
  if (lane == 0) p[row] = 1.f / (1.f + __expf(-s));
}

// ---------------- edge prediction ----------------
__global__ void pred_kernel(const float* __restrict__ p, const int* __restrict__ eli,
                            float* __restrict__ out, int K) {
  int i = blockIdx.x * blockDim.x + threadIdx.x;
  if (i < K) out[i] = p[eli[i]] * p[eli[K + i]];
}

extern "C" void kernel_launch(void* const* d_in, const int* in_sizes, int n_in,
                              void* d_out, int out_size, void* d_ws, size_t ws_size,
                              hipStream_t stream) {
  const float* x       = (const float*)d_in[0];
  const float* seq     = (const float*)d_in[1];
  const int* src       = (const int*)d_in[2];
  const int* dst       = (const int*)d_in[3];
  const int* eli       = (const int*)d_in[4];
  const float* skip_w0 = (const float*)d_in[5];
  const float* skip_b0 = (const float*)d_in[6];
  const float* msg_w0  = (const float*)d_in[7];
  const float* msg_b0  = (const float*)d_in[8];
  const float* skip_w1 = (const float*)d_in[9];
  const float* skip_b1 = (const float*)d_in[10];
  const float* msg_w1  = (const float*)d_in[11];
  const float* msg_b1  = (const float*)d_in[12];
  const float* ipw     = (const float*)d_in[13];
  const float* ipb     = (const float*)d_in[14];
  const float* opw     = (const float*)d_in[15];
  const float* opb     = (const float*)d_in[16];
  const float* ln_g    = (const float*)d_in[17];
  const float* ln_b    = (const float*)d_in[18];
  const float* w1      = (const float*)d_in[19];
  const float* w2      = (const float*)d_in[20];

  const int N  = in_sizes[0] / D;   // 8192
  const int S  = in_sizes[1] / D;   // 2048
  const int E  = in_sizes[2];       // 524288
  const int Kp = in_sizes[4] / 2;   // 100000

  float* ws    = (float*)d_ws;
  float* B0    = ws;                        // agg out -> attention O accumulator
  float* B1    = B0 + (size_t)N * D;
  float* B2    = B1 + (size_t)N * D;
  float* B3    = B2 + (size_t)N * D;        // Q fp32 / mlp hidden
  float* KB    = B3 + (size_t)N * D;
  float* VB    = KB + (size_t)S * D;
  short* Qbf   = (short*)(VB + (size_t)S * D);   // N*D bf16
  short* Kbf   = Qbf + (size_t)N * D;            // S*D bf16
  short* Vt    = Kbf + (size_t)S * D;            // D*S bf16 (transposed)
  float* mrow  = (float*)(Vt + (size_t)D * S);   // 4*N
  float* lbuf  = mrow + 4 * (size_t)N;           // 4*N
  float* dinv  = lbuf + 4 * (size_t)N;
  float* pbuf  = dinv + N;
  int*   MkhI  = (int*)(pbuf + N);               // 4
  int* cnt_src = MkhI + 4;
  int* cnt_dst = cnt_src + N;
  int* row_ptr = cnt_dst + N;                    // N+1
  int* cursor  = row_ptr + (N + 1);
  int* csr_src = cursor + N;                     // E

  float* pred_out = (float*)d_out;
  float* emb_out  = pred_out + Kp;

  hipMemsetAsync(cnt_src, 0, 2 * (size_t)N * sizeof(int), stream);
  hipMemsetAsync(MkhI, 0, 4 * sizeof(int), stream);
  hipMemsetAsync(lbuf, 0, 4 * (size_t)N * sizeof(float), stream);

  count_kernel<<<512, 256, 0, stream>>>(src, dst, cnt_src, cnt_dst, E);
  scan_kernel<<<1, 256, 0, stream>>>(cnt_src, cnt_dst, dinv, row_ptr, cursor, N);
  scatter_kernel<<<512, 256, 0, stream>>>(src, dst, cursor, csr_src, E);

  // GCN layers
  agg_kernel<<<N, 128, 0, stream>>>(x, dinv, row_ptr, csr_src, B0);
  gemm128_kernel<<<N / 32, 256, 0, stream>>>(B0, msg_w0, msg_b0, x, skip_w0, skip_b0, nullptr, B1, 0);
  agg_kernel<<<N, 128, 0, stream>>>(B1, dinv, row_ptr, csr_src, B0);
  gemm128_kernel<<<N / 32, 256, 0, stream>>>(B0, msg_w1, msg_b1, B1, skip_w1, skip_b1, nullptr, B2, 0);

  // projections
  gemm128_kernel<<<N / 32, 256, 0, stream>>>(B2, ipw, ipb, nullptr, nullptr, nullptr, nullptr, B3, 0);
  gemm128_kernel<<<S / 32, 256, 0, stream>>>(seq, ipw + D * D, ipb + D, nullptr, nullptr, nullptr, nullptr, KB, 0);
  gemm128_kernel<<<S / 32, 256, 0, stream>>>(seq, ipw + 2 * D * D, ipb + 2 * D, nullptr, nullptr, nullptr, nullptr, VB, 0);

  // bf16 prep + shift bounds
  kv_prep_kernel<<<S / 32, 256, 0, stream>>>(KB, VB, Kbf, Vt, MkhI, S);
  q_prep_kernel<<<N / 16, 256, 0, stream>>>(B3, MkhI, Qbf, mrow, N);

  // attention (split-S, atomic accumulate into zeroed B0)
  hipMemsetAsync(B0, 0, (size_t)N * D * sizeof(float), stream);
  dim3 fgrid(N / 32, 4, 4);
  flash_kernel<<<fgrid, 64, 0, stream>>>(Qbf, Kbf, Vt, mrow, B0, lbuf, N, S);
  attn_norm_kernel<<<N * 32 / 256, 256, 0, stream>>>(B0, lbuf, N);

  // out_proj + residual, LN+L2, MLP, prediction
  gemm128_kernel<<<N / 32, 256, 0, stream>>>(B0, opw, opb, nullptr, nullptr, nullptr, B2, B1, 0);
  ln_l2_kernel<<<N, 64, 0, stream>>>(B1, ln_g, ln_b, emb_out);
  gemm128_kernel<<<N / 32, 256, 0, stream>>>(emb_out, w1, nullptr, nullptr, nullptr, nullptr, nullptr, B3, 1);
  mlp2_kernel<<<N / 4, 256, 0, stream>>>(B3, w2, pbuf, N);
  pred_kernel<<<(Kp + 255) / 256, 256, 0, stream>>>(pbuf, eli, pred_out, Kp);
}

// Round 4
// 361.135 us; speedup vs baseline: 1.6685x; 1.1183x over previous
//
#include <hip/hip_runtime.h>
#include <math.h>

#define D 128

typedef short bf16x4 __attribute__((ext_vector_type(4)));
typedef short bf16x8 __attribute__((ext_vector_type(8)));
typedef float f32x4 __attribute__((ext_vector_type(4)));

__device__ __forceinline__ float4 ld4(const float* p) { return *(const float4*)p; }

__device__ __forceinline__ short f2bf(float f) {
  unsigned u = __float_as_uint(f);
  u += 0x7FFF + ((u >> 16) & 1);
  return (short)(u >> 16);
}

// ---------------- weight prep: fp32 -> bf16, 9 DxD matrices ----------------
struct WSrc { const float* p[9]; };
__global__ __launch_bounds__(256) void wprep_kernel(WSrc ws, short* __restrict__ dst) {
  int m = blockIdx.y;
  int i = (blockIdx.x * 256 + threadIdx.x) * 4;   // grid.x=16 -> 16384 elems
  float4 v = ld4(ws.p[m] + i);
  bf16x4 o = {f2bf(v.x), f2bf(v.y), f2bf(v.z), f2bf(v.w)};
  *(bf16x4*)&dst[m * 16384 + i] = o;
}

// ---------------- degree counting ----------------
__global__ void count_kernel(const int* __restrict__ src, const int* __restrict__ dst,
                             int* __restrict__ cnt_src, int* __restrict__ cnt_dst, int E) {
  int i = blockIdx.x * blockDim.x + threadIdx.x;
  int stride = gridDim.x * blockDim.x;
  for (; i < E; i += stride) {
    atomicAdd(&cnt_src[src[i]], 1);
    atomicAdd(&cnt_dst[dst[i]], 1);
  }
}

// ---------------- scan: row_ptr/cursor + dinv ----------------
__global__ __launch_bounds__(256) void scan_kernel(
    const int* __restrict__ cnt_src, const int* __restrict__ cnt_dst,
    float* __restrict__ dinv, int* __restrict__ row_ptr, int* __restrict__ cursor, int N) {
  __shared__ int part[256];
  int t = threadIdx.x;
  int chunk = (N + 255) / 256;
  int base = t * chunk;
  int sum = 0;
  for (int i = 0; i < chunk; ++i) {
    int idx = base + i;
    if (idx < N) sum += cnt_dst[idx];
  }
  part[t] = sum;
  __syncthreads();
  if (t == 0) {
    int run = 0;
    for (int i = 0; i < 256; ++i) { int v = part[i]; part[i] = run; run += v; }
  }
  __syncthreads();
  int run = part[t];
  for (int i = 0; i < chunk; ++i) {
    int idx = base + i;
    if (idx < N) {
      int v = cnt_dst[idx];
      row_ptr[idx] = run; cursor[idx] = run; run += v;
      int dg = cnt_src[idx];
      dinv[idx] = dg > 0 ? rsqrtf((float)dg) : 0.f;
    }
  }
  if (t == 255) row_ptr[N] = run;
}

// ---------------- CSR scatter ----------------
__global__ void scatter_kernel(const int* __restrict__ src, const int* __restrict__ dst,
                               int* __restrict__ cursor, int* __restrict__ csr_src, int E) {
  int i = blockIdx.x * blockDim.x + threadIdx.x;
  int stride = gridDim.x * blockDim.x;
  for (; i < E; i += stride) {
    int pos = atomicAdd(&cursor[dst[i]], 1);
    csr_src[pos] = src[i];
  }
}

// ---------------- GCN aggregation (block per dst node, float4 lanes) ----------------
__global__ __launch_bounds__(128) void agg_kernel(
    const float* __restrict__ feats, const float* __restrict__ dinv,
    const int* __restrict__ row_ptr, const int* __restrict__ csr_src,
    float* __restrict__ out) {
  __shared__ int idx[128];
  __shared__ float dv[128];
  __shared__ float4 red[128];
  int n = blockIdx.x, t = threadIdx.x;
  int lane = t & 31, grp = t >> 5;
  int beg = row_ptr[n], end = row_ptr[n + 1];
  float4 acc = {0.f, 0.f, 0.f, 0.f};
  for (int c = beg; c < end; c += 128) {
    int j = c + t;
    if (j < end) { int s = csr_src[j]; idx[t] = s; dv[t] = dinv[s]; }
    __syncthreads();
    int cnt = min(128, end - c);
    for (int e = grp; e < cnt; e += 4) {
      float4 v = ld4(&feats[(size_t)idx[e] * D + lane * 4]);
      float w = dv[e];
      acc.x += v.x * w; acc.y += v.y * w; acc.z += v.z * w; acc.w += v.w * w;
    }
    __syncthreads();
  }
  red[t] = acc;
  __syncthreads();
  if (t < 32) {
    float4 a = red[t], b = red[32 + t], c2 = red[64 + t], d2 = red[96 + t];
    float w = dinv[n];
    float4 o2 = {(a.x + b.x + c2.x + d2.x) * w, (a.y + b.y + c2.y + d2.y) * w,
                 (a.z + b.z + c2.z + d2.z) * w, (a.w + b.w + c2.w + d2.w) * w};
    *(float4*)&out[(size_t)n * D + t * 4] = o2;
  }
}

// ---------------- MFMA GEMM core: C = act(A1@W1^T [+ A2@W2^T] + b1 [+b2] [+R]) ----------------
// block 256 = 4 waves; 32-row tile; wave w: row-tile rt=w&1, col-half ch=w>>1 (4 n-tiles of 16)
// As stride 136 bf16 (272B): rows advance 4 banks -> balanced b128 reads and writes.
__device__ __forceinline__ void gemm_core(
    const float* __restrict__ A1, const short* __restrict__ W1, const float* __restrict__ b1,
    const float* __restrict__ A2, const short* __restrict__ W2, const float* __restrict__ b2,
    const float* __restrict__ Rres, float* __restrict__ C, int act, int m0, short* As) {
  const int t = threadIdx.x;
  const int w = t >> 6, lane = t & 63, quad = lane >> 4, r16 = lane & 15;
  const int rt = w & 1, ch = w >> 1;
  f32x4 acc[4];
  f32x4 zz = {0.f, 0.f, 0.f, 0.f};
  acc[0] = zz; acc[1] = zz; acc[2] = zz; acc[3] = zz;
  for (int pair = 0; pair < 2; ++pair) {
    const float* A = pair ? A2 : A1;
    const short* W = pair ? W2 : W1;
    if (!A) break;
    if (pair) __syncthreads();
    {
      int row = t >> 3, seg = t & 7;
      const float* ap = &A[(size_t)(m0 + row) * D + seg * 16];
      float4 v0 = ld4(ap), v1 = ld4(ap + 4), v2 = ld4(ap + 8), v3 = ld4(ap + 12);
      bf16x8 w0 = {f2bf(v0.x), f2bf(v0.y), f2bf(v0.z), f2bf(v0.w),
                   f2bf(v1.x), f2bf(v1.y), f2bf(v1.z), f2bf(v1.w)};
      bf16x8 w1v = {f2bf(v2.x), f2bf(v2.y), f2bf(v2.z), f2bf(v2.w),
                    f2bf(v3.x), f2bf(v3.y), f2bf(v3.z), f2bf(v3.w)};
      *(bf16x8*)&As[row * 136 + seg * 16] = w0;
      *(bf16x8*)&As[row * 136 + seg * 16 + 8] = w1v;
    }
    __syncthreads();
#pragma unroll
    for (int ks = 0; ks < 4; ++ks) {
      bf16x8 af = *(bf16x8*)&As[(rt * 16 + r16) * 136 + ks * 32 + quad * 8];
#pragma unroll
      for (int nt = 0; nt < 4; ++nt) {
        bf16x8 bw = *(const bf16x8*)&W[(size_t)(ch * 64 + nt * 16 + r16) * D + ks * 32 + quad * 8];
        acc[nt] = __builtin_amdgcn_mfma_f32_16x16x32_bf16(af, bw, acc[nt], 0, 0, 0);
      }
    }
  }
#pragma unroll
  for (int nt = 0; nt < 4; ++nt) {
    int col = ch * 64 + nt * 16 + r16;
    float bias = 0.f;
    if (b1) bias += b1[col];
    if (b2) bias += b2[col];
#pragma unroll
    for (int g = 0; g < 4; ++g) {
      int row = m0 + rt * 16 + quad * 4 + g;
      float v = acc[nt][g] + bias;
      if (Rres) v += Rres[(size_t)row * D + col];
      if (act) v = fmaxf(v, 0.f);
      C[(size_t)row * D + col] = v;
    }
  }
}

__global__ __launch_bounds__(256) void gemm_bf16_kernel(
    const float* A1, const short* W1, const float* b1,
    const float* A2, const short* W2, const float* b2,
    const float* Rres, float* C, int act) {
  __shared__ short As[32 * 136];
  gemm_core(A1, W1, b1, A2, W2, b2, Rres, C, act, blockIdx.x * 32, As);
}

// fused Q/K/V projections: blocks [0,256) Q over X(8192), [256,320) K over seq, [320,384) V
__global__ __launch_bounds__(256) void qkv_kernel(
    const float* __restrict__ X, const float* __restrict__ seq,
    const short* __restrict__ Wq, const short* __restrict__ Wk, const short* __restrict__ Wv,
    const float* __restrict__ ipb, float* Qo, float* Ko, float* Vo) {
  __shared__ short As[32 * 136];
  int b = blockIdx.x;
  if (b < 256)
    gemm_core(X, Wq, ipb, nullptr, nullptr, nullptr, nullptr, Qo, 0, b * 32, As);
  else if (b < 320)
    gemm_core(seq, Wk, ipb + 128, nullptr, nullptr, nullptr, nullptr, Ko, 0, (b - 256) * 32, As);
  else
    gemm_core(seq, Wv, ipb + 256, nullptr, nullptr, nullptr, nullptr, Vo, 0, (b - 320) * 32, As);
}

// ---------------- K/V prep: fp32 -> bf16, V transposed, per-head max |k|^2 ----------------
__global__ __launch_bounds__(256) void kv_prep_kernel(
    const float* __restrict__ KB, const float* __restrict__ VB,
    short* __restrict__ Kbf, short* __restrict__ Vt, int* __restrict__ MkhI, int S) {
  __shared__ short VtS[128 * 40];
  __shared__ float kn[128];
  const int t = threadIdx.x;
  const int s0 = blockIdx.x * 32;
  if (t < 128) kn[t] = 0.f;
  __syncthreads();
#pragma unroll
  for (int i = 0; i < 4; ++i) {
    int id = t + i * 256;
    int key = id >> 5, d4 = (id & 31) * 4;
    float4 kv = ld4(&KB[(size_t)(s0 + key) * D + d4]);
    bf16x4 kw = {f2bf(kv.x), f2bf(kv.y), f2bf(kv.z), f2bf(kv.w)};
    *(bf16x4*)&Kbf[(size_t)(s0 + key) * D + d4] = kw;
    float ss = kv.x * kv.x + kv.y * kv.y + kv.z * kv.z + kv.w * kv.w;
    atomicAdd(&kn[key * 4 + (d4 >> 5)], ss);
    float4 vv = ld4(&VB[(size_t)(s0 + key) * D + d4]);
    VtS[(d4 + 0) * 40 + key] = f2bf(vv.x);
    VtS[(d4 + 1) * 40 + key] = f2bf(vv.y);
    VtS[(d4 + 2) * 40 + key] = f2bf(vv.z);
    VtS[(d4 + 3) * 40 + key] = f2bf(vv.w);
  }
  __syncthreads();
  if (t < 128) {
    int key = t >> 2, h = t & 3;
    atomicMax(&MkhI[h], __float_as_int(kn[key * 4 + h]));
  }
  int dim = t >> 1, half = t & 1;
  bf16x8 v0 = *(bf16x8*)&VtS[dim * 40 + half * 16];
  bf16x8 v1 = *(bf16x8*)&VtS[dim * 40 + half * 16 + 8];
  *(bf16x8*)&Vt[(size_t)dim * S + s0 + half * 16] = v0;
  *(bf16x8*)&Vt[(size_t)dim * S + s0 + half * 16 + 8] = v1;
}

// ---------------- Q prep ----------------
__global__ __launch_bounds__(256) void q_prep_kernel(
    const float* __restrict__ Qf, const int* __restrict__ MkhI,
    short* __restrict__ Qbf, float* __restrict__ mrow, int N) {
  const int t = threadIdx.x;
  const int r = blockIdx.x * 16 + (t >> 4);
  const int l16 = t & 15;
  const float s32 = 0.17677669529663687f;
  const float* qp = &Qf[(size_t)r * D + l16 * 8];
  float4 a = ld4(qp), b = ld4(qp + 4);
  a.x *= s32; a.y *= s32; a.z *= s32; a.w *= s32;
  b.x *= s32; b.y *= s32; b.z *= s32; b.w *= s32;
  bf16x8 w = {f2bf(a.x), f2bf(a.y), f2bf(a.z), f2bf(a.w),
              f2bf(b.x), f2bf(b.y), f2bf(b.z), f2bf(b.w)};
  *(bf16x8*)&Qbf[(size_t)r * D + l16 * 8] = w;
  float ss = a.x * a.x + a.y * a.y + a.z * a.z + a.w * a.w +
             b.x * b.x + b.y * b.y + b.z * b.z + b.w * b.w;
  ss += __shfl_xor(ss, 1);
  ss += __shfl_xor(ss, 2);
  if ((l16 & 3) == 0) {
    int h = l16 >> 2;
    float mk = __int_as_float(MkhI[h]);
    mrow[h * N + r] = sqrtf(ss) * sqrtf(fmaxf(mk, 0.f));
  }
}

// ---------------- MFMA flash attention, fixed-shift softmax, split-S=2, no atomics ----------------
__global__ __launch_bounds__(64, 4) void flash_kernel(
    const short* __restrict__ Qbf, const short* __restrict__ Kbf, const short* __restrict__ Vt,
    const float* __restrict__ mrow, float* __restrict__ O0, float* __restrict__ O1,
    float* __restrict__ lbuf, int N, int S) {
  __shared__ short Ps[32 * 72];
  const int lane = threadIdx.x;
  const int quad = lane >> 4, r16 = lane & 15;
  const int n0 = blockIdx.x * 32;
  const int h = blockIdx.y;
  const int sp = blockIdx.z;
  float* O = sp ? O1 : O0;

  bf16x8 aq[2];
  aq[0] = *(const bf16x8*)&Qbf[(size_t)(n0 + r16) * D + h * 32 + quad * 8];
  aq[1] = *(const bf16x8*)&Qbf[(size_t)(n0 + 16 + r16) * D + h * 32 + quad * 8];

  float msh[2][4];
#pragma unroll
  for (int rt = 0; rt < 2; ++rt)
#pragma unroll
    for (int g = 0; g < 4; ++g)
      msh[rt][g] = fminf(mrow[h * N + n0 + rt * 16 + quad * 4 + g], 40.f);

  f32x4 o[2][2], lac[2];
  f32x4 zz = {0.f, 0.f, 0.f, 0.f};
  o[0][0] = zz; o[0][1] = zz; o[1][0] = zz; o[1][1] = zz;
  lac[0] = zz; lac[1] = zz;
  bf16x8 ones = {(short)0x3F80, (short)0x3F80, (short)0x3F80, (short)0x3F80,
                 (short)0x3F80, (short)0x3F80, (short)0x3F80, (short)0x3F80};

  const int span = S >> 1;
  const int c0 = sp * span;
  for (int c = c0; c < c0 + span; c += 64) {
    f32x4 s[2][4];
#pragma unroll
    for (int kt = 0; kt < 4; ++kt) {
      bf16x8 bk = *(const bf16x8*)&Kbf[(size_t)(c + kt * 16 + r16) * D + h * 32 + quad * 8];
      f32x4 z = {0.f, 0.f, 0.f, 0.f};
      s[0][kt] = __builtin_amdgcn_mfma_f32_16x16x32_bf16(aq[0], bk, z, 0, 0, 0);
      s[1][kt] = __builtin_amdgcn_mfma_f32_16x16x32_bf16(aq[1], bk, z, 0, 0, 0);
    }
#pragma unroll
    for (int rt = 0; rt < 2; ++rt)
#pragma unroll
      for (int kt = 0; kt < 4; ++kt)
#pragma unroll
        for (int g = 0; g < 4; ++g) {
          float p = __expf(s[rt][kt][g] - msh[rt][g]);
          Ps[(rt * 16 + quad * 4 + g) * 72 + kt * 16 + r16] = f2bf(p);
        }
    // same-wave LDS round-trip (lgkmcnt only, no barrier)
#pragma unroll
    for (int rt = 0; rt < 2; ++rt)
#pragma unroll
      for (int kc = 0; kc < 2; ++kc) {
        bf16x8 ap = *(bf16x8*)&Ps[(rt * 16 + r16) * 72 + kc * 32 + quad * 8];
        lac[rt] = __builtin_amdgcn_mfma_f32_16x16x32_bf16(ap, ones, lac[rt], 0, 0, 0);
#pragma unroll
        for (int nt = 0; nt < 2; ++nt) {
          bf16x8 bv = *(const bf16x8*)&Vt[(size_t)(h * 32 + nt * 16 + r16) * S + c + kc * 32 + quad * 8];
          o[rt][nt] = __builtin_amdgcn_mfma_f32_16x16x32_bf16(ap, bv, o[rt][nt], 0, 0, 0);
        }
      }
  }
#pragma unroll
  for (int rt = 0; rt < 2; ++rt)
#pragma unroll
    for (int g = 0; g < 4; ++g) {
      int row = n0 + rt * 16 + quad * 4 + g;
#pragma unroll
      for (int nt = 0; nt < 2; ++nt)
        O[(size_t)row * D + h * 32 + nt * 16 + r16] = o[rt][nt][g];
      if (r16 == 0) lbuf[(sp * 4 + h) * N + row] = lac[rt][g];
    }
}

// ---------------- merge splits + normalize ----------------
__global__ __launch_bounds__(256) void attn_merge_kernel(
    const float* __restrict__ O0, const float* __restrict__ O1,
    const float* __restrict__ lbuf, float* __restrict__ out, int N) {
  int tid = blockIdx.x * 256 + threadIdx.x;   // N*32
  int row = tid >> 5, c4 = (tid & 31) * 4, h = c4 >> 5;
  float inv = 1.f / (lbuf[h * N + row] + lbuf[(4 + h) * N + row]);
  float4 a = ld4(&O0[(size_t)row * D + c4]);
  float4 b = ld4(&O1[(size_t)row * D + c4]);
  float4 v = {(a.x + b.x) * inv, (a.y + b.y) * inv, (a.z + b.z) * inv, (a.w + b.w) * inv};
  *(float4*)&out[(size_t)row * D + c4] = v;
}

// ---------------- LayerNorm + L2 normalize (1 wave per row) ----------------
__global__ __launch_bounds__(64) void ln_l2_kernel(
    const float* __restrict__ X, const float* __restrict__ g, const float* __restrict__ b,
    float* __restrict__ out) {
  int n = blockIdx.x, t = threadIdx.x;
  float2 v = *(const float2*)&X[n * D + t * 2];
  float s = v.x + v.y;
  for (int off = 32; off; off >>= 1) s += __shfl_xor(s, off);
  float mu = s * (1.f / 128.f);
  float dx = v.x - mu, dy = v.y - mu;
  float q = dx * dx + dy * dy;
  for (int off = 32; off; off >>= 1) q += __shfl_xor(q, off);
  float rs = rsqrtf(q * (1.f / 128.f) + 1e-5f);
  float2 gg = *(const float2*)&g[t * 2];
  float2 bb = *(const float2*)&b[t * 2];
  float yx = dx * rs * gg.x + bb.x;
  float yy = dy * rs * gg.y + bb.y;
  float nn = yx * yx + yy * yy;
  for (int off = 32; off; off >>= 1) nn += __shfl_xor(nn, off);
  float inv = 1.f / fmaxf(sqrtf(nn), 1e-12f);
  float2 ov = {yx * inv, yy * inv};
  *(float2*)&out[n * D + t * 2] = ov;
}

// ---------------- MLP layer 2 + sigmoid ----------------
__global__ __launch_bounds__(256) void mlp2_kernel(
    const float* __restrict__ H, const float* __restrict__ w2, float* __restrict__ p, int M) {
  int row = blockIdx.x * 4 + (threadIdx.x >> 6);
  int lane = threadIdx.x & 63;
  if (row >= M) return;
  float2 h2 = *(const float2*)&H[row * D + lane * 2];
  float2 w = *(const float2*)&w2[lane * 2];
  float s = h2.x * w.x + h2.y * w.y;
  for (int off = 32; off; off >>= 1) s += __shfl_xor(s, off);
  if (lane == 0) p[row] = 1.f / (1.f + __expf(-s));
}

// ---------------- edge prediction ----------------
__global__ void pred_kernel(const float* __restrict__ p, const int* __restrict__ eli,
                            float* __restrict__ out, int K) {
  int i = blockIdx.x * blockDim.x + threadIdx.x;
  if (i < K) out[i] = p[eli[i]] * p[eli[K + i]];
}

extern "C" void kernel_launch(void* const* d_in, const int* in_sizes, int n_in,
                              void* d_out, int out_size, void* d_ws, size_t ws_size,
                              hipStream_t stream) {
  const float* x       = (const float*)d_in[0];
  const float* seq     = (const float*)d_in[1];
  const int* src       = (const int*)d_in[2];
  const int* dst       = (const int*)d_in[3];
  const int* eli       = (const int*)d_in[4];
  const float* skip_w0 = (const float*)d_in[5];
  const float* skip_b0 = (const float*)d_in[6];
  const float* msg_w0  = (const float*)d_in[7];
  const float* msg_b0  = (const float*)d_in[8];
  const float* skip_w1 = (const float*)d_in[9];
  const float* skip_b1 = (const float*)d_in[10];
  const float* msg_w1  = (const float*)d_in[11];
  const float* msg_b1  = (const float*)d_in[12];
  const float* ipw     = (const float*)d_in[13];
  const float* ipb     = (const float*)d_in[14];
  const float* opw     = (const float*)d_in[15];
  const float* opb     = (const float*)d_in[16];
  const float* ln_g    = (const float*)d_in[17];
  const float* ln_b    = (const float*)d_in[18];
  const float* w1      = (const float*)d_in[19];
  const float* w2      = (const float*)d_in[20];

  const int N  = in_sizes[0] / D;   // 8192
  const int S  = in_sizes[1] / D;   // 2048
  const int E  = in_sizes[2];       // 524288
  const int Kp = in_sizes[4] / 2;   // 100000

  float* ws    = (float*)d_ws;
  float* B0    = ws;                        // agg scratch / O-split0 / mlp hidden
  float* B1    = B0 + (size_t)N * D;        // gcn1 out / O-split1 / pre-LN
  float* B2    = B1 + (size_t)N * D;        // gcn2 out (attention input + residual)
  float* B3    = B2 + (size_t)N * D;        // Q fp32 / merged attn out
  float* KB    = B3 + (size_t)N * D;
  float* VB    = KB + (size_t)S * D;
  short* Qbf   = (short*)(VB + (size_t)S * D);   // N*D bf16
  short* Kbf   = Qbf + (size_t)N * D;            // S*D bf16
  short* Vt    = Kbf + (size_t)S * D;            // D*S bf16
  short* Wbf   = Vt + (size_t)D * S;             // 9 * 16384 bf16
  float* mrow  = (float*)(Wbf + 9 * 16384);      // 4*N
  float* lbuf  = mrow + 4 * (size_t)N;           // 8*N (2 splits x 4 heads)
  float* dinv  = lbuf + 8 * (size_t)N;
  float* pbuf  = dinv + N;
  int*   MkhI  = (int*)(pbuf + N);               // 4
  int* cnt_src = MkhI + 4;
  int* cnt_dst = cnt_src + N;
  int* row_ptr = cnt_dst + N;                    // N+1
  int* cursor  = row_ptr + (N + 1);
  int* csr_src = cursor + N;                     // E

  float* pred_out = (float*)d_out;
  float* emb_out  = pred_out + Kp;

  const short* w_skip0 = Wbf + 0 * 16384;
  const short* w_msg0  = Wbf + 1 * 16384;
  const short* w_skip1 = Wbf + 2 * 16384;
  const short* w_msg1  = Wbf + 3 * 16384;
  const short* w_q     = Wbf + 4 * 16384;
  const short* w_k     = Wbf + 5 * 16384;
  const short* w_v     = Wbf + 6 * 16384;
  const short* w_op    = Wbf + 7 * 16384;
  const short* w_m1    = Wbf + 8 * 16384;

  hipMemsetAsync(cnt_src, 0, 2 * (size_t)N * sizeof(int), stream);
  hipMemsetAsync(MkhI, 0, 4 * sizeof(int), stream);

  WSrc wsrc;
  wsrc.p[0] = skip_w0; wsrc.p[1] = msg_w0; wsrc.p[2] = skip_w1; wsrc.p[3] = msg_w1;
  wsrc.p[4] = ipw; wsrc.p[5] = ipw + D * D; wsrc.p[6] = ipw + 2 * D * D;
  wsrc.p[7] = opw; wsrc.p[8] = w1;
  dim3 wgrid(16, 9);
  wprep_kernel<<<wgrid, 256, 0, stream>>>(wsrc, (short*)Wbf);

  count_kernel<<<512, 256, 0, stream>>>(src, dst, cnt_src, cnt_dst, E);
  scan_kernel<<<1, 256, 0, stream>>>(cnt_src, cnt_dst, dinv, row_ptr, cursor, N);
  scatter_kernel<<<512, 256, 0, stream>>>(src, dst, cursor, csr_src, E);

  // GCN layers (dual-pair MFMA GEMMs)
  agg_kernel<<<N, 128, 0, stream>>>(x, dinv, row_ptr, csr_src, B0);
  gemm_bf16_kernel<<<N / 32, 256, 0, stream>>>(B0, w_msg0, msg_b0, x, w_skip0, skip_b0, nullptr, B1, 0);
  agg_kernel<<<N, 128, 0, stream>>>(B1, dinv, row_ptr, csr_src, B0);
  gemm_bf16_kernel<<<N / 32, 256, 0, stream>>>(B0, w_msg1, msg_b1, B1, w_skip1, skip_b1, nullptr, B2, 0);

  // fused Q/K/V projections
  qkv_kernel<<<N / 32 + 2 * (S / 32), 256, 0, stream>>>(B2, seq, w_q, w_k, w_v, ipb, B3, KB, VB);

  // bf16 prep + shift bounds
  kv_prep_kernel<<<S / 32, 256, 0, stream>>>(KB, VB, Kbf, Vt, MkhI, S);
  q_prep_kernel<<<N / 16, 256, 0, stream>>>(B3, MkhI, Qbf, mrow, N);

  // attention: split-S=2, plain stores into B0/B1, merge into B3
  dim3 fgrid(N / 32, 4, 2);
  flash_kernel<<<fgrid, 64, 0, stream>>>(Qbf, Kbf, Vt, mrow, B0, B1, lbuf, N, S);
  attn_merge_kernel<<<N * 32 / 256, 256, 0, stream>>>(B0, B1, lbuf, B3, N);

  // out_proj + residual(B2) -> B1; LN+L2 -> emb; MLP; prediction
  gemm_bf16_kernel<<<N / 32, 256, 0, stream>>>(B3, w_op, opb, nullptr, nullptr, nullptr, B2, B1, 0);
  ln_l2_kernel<<<N, 64, 0, stream>>>(B1, ln_g, ln_b, emb_out);
  gemm_bf16_kernel<<<N / 32, 256, 0, stream>>>(emb_out, w_m1, nullptr, nullptr, nullptr, nullptr, nullptr, B0, 1);
  mlp2_kernel<<<N / 4, 256, 0, stream>>>(B0, w2, pbuf, N);
  pred_kernel<<<(Kp + 255) / 256, 256, 0, stream>>>(pbuf, eli, pred_out, Kp);
}

// Round 5
// 295.289 us; speedup vs baseline: 2.0406x; 1.2230x over previous
//
#include <hip/hip_runtime.h>
#include <math.h>

#define D 128
#define HB 128   // histogram blocks (E/HB edges per block)

typedef short bf16x4 __attribute__((ext_vector_type(4)));
typedef short bf16x8 __attribute__((ext_vector_type(8)));
typedef float f32x4 __attribute__((ext_vector_type(4)));

__device__ __forceinline__ float4 ld4(const float* p) { return *(const float4*)p; }

__device__ __forceinline__ short f2bf(float f) {
  unsigned u = __float_as_uint(f);
  u += 0x7FFF + ((u >> 16) & 1);
  return (short)(u >> 16);
}

// ---------------- weight prep: fp32 -> bf16, 9 DxD matrices ----------------
struct WSrc { const float* p[9]; };
__global__ __launch_bounds__(256) void wprep_kernel(WSrc ws, short* __restrict__ dst) {
  int m = blockIdx.y;
  int i = (blockIdx.x * 256 + threadIdx.x) * 4;
  float4 v = ld4(ws.p[m] + i);
  bf16x4 o = {f2bf(v.x), f2bf(v.y), f2bf(v.z), f2bf(v.w)};
  *(bf16x4*)&dst[m * 16384 + i] = o;
}

// ---------------- CSR build, atomic-free (LDS-privatized histograms) ----------------
__global__ __launch_bounds__(256) void hist_kernel(
    const int* __restrict__ src, const int* __restrict__ dst,
    int* __restrict__ histd, int* __restrict__ hists, int E) {
  __shared__ int hd[8192];
  __shared__ int hs[8192];
  int t = threadIdx.x;
  for (int i = t; i < 8192; i += 256) { hd[i] = 0; hs[i] = 0; }
  __syncthreads();
  int per = E / HB;
  int b0 = blockIdx.x * per;
  for (int j = 0; j < per; j += 256) {
    int i = b0 + j + t;
    atomicAdd(&hd[dst[i]], 1);   // LDS atomics only
    atomicAdd(&hs[src[i]], 1);
  }
  __syncthreads();
  for (int i = t; i < 8192; i += 256) {
    histd[blockIdx.x * 8192 + i] = hd[i];
    hists[blockIdx.x * 8192 + i] = hs[i];
  }
}

__global__ __launch_bounds__(256) void colsum_kernel(
    const int* __restrict__ histd, const int* __restrict__ hists,
    int* __restrict__ deg, float* __restrict__ dinv) {
  int v = blockIdx.x * 256 + threadIdx.x;
  int sd = 0, ss = 0;
  for (int b = 0; b < HB; ++b) { sd += histd[b * 8192 + v]; ss += hists[b * 8192 + v]; }
  deg[v] = sd;
  dinv[v] = ss > 0 ? rsqrtf((float)ss) : 0.f;
}

__global__ __launch_bounds__(1024) void scan8k_kernel(
    const int* __restrict__ deg, int* __restrict__ row_ptr, int N) {
  __shared__ int wtot[16];
  int t = threadIdx.x;
  int lane = t & 63, wv = t >> 6;
  int v0 = t * 8;
  int x[8]; int s = 0;
#pragma unroll
  for (int j = 0; j < 8; ++j) { x[j] = s; s += deg[v0 + j]; }
  int incl = s;
  for (int off = 1; off < 64; off <<= 1) {
    int y = __shfl_up(incl, off);
    if (lane >= off) incl += y;
  }
  if (lane == 63) wtot[wv] = incl;
  __syncthreads();
  if (t == 0) { int run = 0; for (int i = 0; i < 16; ++i) { int v = wtot[i]; wtot[i] = run; run += v; } }
  __syncthreads();
  int base = wtot[wv] + (incl - s);
#pragma unroll
  for (int j = 0; j < 8; ++j) row_ptr[v0 + j] = base + x[j];
  if (t == 1023) row_ptr[N] = base + s;
}

__global__ __launch_bounds__(256) void basegen_kernel(
    const int* __restrict__ histd, const int* __restrict__ row_ptr,
    int* __restrict__ base_arr) {
  int v = blockIdx.x * 256 + threadIdx.x;
  int run = row_ptr[v];
  for (int b = 0; b < HB; ++b) { base_arr[b * 8192 + v] = run; run += histd[b * 8192 + v]; }
}

__global__ __launch_bounds__(256) void scatter2_kernel(
    const int* __restrict__ src, const int* __restrict__ dst,
    const int* __restrict__ base_arr, int* __restrict__ csr_src, int E) {
  __shared__ int lh[8192];
  int t = threadIdx.x;
  for (int i = t; i < 8192; i += 256) lh[i] = 0;
  __syncthreads();
  int per = E / HB;
  int b0 = blockIdx.x * per;
  const int* __restrict__ bb = &base_arr[blockIdx.x * 8192];
  for (int j = 0; j < per; j += 256) {
    int i = b0 + j + t;
    int v = dst[i];
    int r = atomicAdd(&lh[v], 1);   // LDS atomic, returns local rank
    csr_src[bb[v] + r] = src[i];
  }
}

// ---------------- GCN aggregation (block per dst node, float4 lanes) ----------------
__global__ __launch_bounds__(128) void agg_kernel(
    const float* __restrict__ feats, const float* __restrict__ dinv,
    const int* __restrict__ row_ptr, const int* __restrict__ csr_src,
    float* __restrict__ out) {
  __shared__ int idx[128];
  __shared__ float dv[128];
  __shared__ float4 red[128];
  int n = blockIdx.x, t = threadIdx.x;
  int lane = t & 31, grp = t >> 5;
  int beg = row_ptr[n], end = row_ptr[n + 1];
  float4 acc = {0.f, 0.f, 0.f, 0.f};
  for (int c = beg; c < end; c += 128) {
    int j = c + t;
    if (j < end) { int s = csr_src[j]; idx[t] = s; dv[t] = dinv[s]; }
    __syncthreads();
    int cnt = min(128, end - c);
    for (int e = grp; e < cnt; e += 4) {
      float4 v = ld4(&feats[(size_t)idx[e] * D + lane * 4]);
      float w = dv[e];
      acc.x += v.x * w; acc.y += v.y * w; acc.z += v.z * w; acc.w += v.w * w;
    }
    __syncthreads();
  }
  red[t] = acc;
  __syncthreads();
  if (t < 32) {
    float4 a = red[t], b = red[32 + t], c2 = red[64 + t], d2 = red[96 + t];
    float w = dinv[n];
    float4 o2 = {(a.x + b.x + c2.x + d2.x) * w, (a.y + b.y + c2.y + d2.y) * w,
                 (a.z + b.z + c2.z + d2.z) * w, (a.w + b.w + c2.w + d2.w) * w};
    *(float4*)&out[(size_t)n * D + t * 4] = o2;
  }
}

// ---------------- MFMA helpers ----------------
__device__ __forceinline__ void mfma_accum(const short* As, const short* __restrict__ W,
                                           int rt, int ch, int quad, int r16, f32x4* acc) {
#pragma unroll
  for (int ks = 0; ks < 4; ++ks) {
    bf16x8 af = *(bf16x8*)&As[(rt * 16 + r16) * 136 + ks * 32 + quad * 8];
#pragma unroll
    for (int nt = 0; nt < 4; ++nt) {
      bf16x8 bw = *(const bf16x8*)&W[(size_t)(ch * 64 + nt * 16 + r16) * D + ks * 32 + quad * 8];
      acc[nt] = __builtin_amdgcn_mfma_f32_16x16x32_bf16(af, bw, acc[nt], 0, 0, 0);
    }
  }
}

// ---------------- MFMA GEMM core: C = act(A1@W1^T [+ A2@W2^T] + b1 [+b2] [+R]) ----------------
__device__ __forceinline__ void gemm_core(
    const float* __restrict__ A1, const short* __restrict__ W1, const float* __restrict__ b1,
    const float* __restrict__ A2, const short* __restrict__ W2, const float* __restrict__ b2,
    const float* __restrict__ Rres, float* __restrict__ C, int act, int m0, short* As) {
  const int t = threadIdx.x;
  const int w = t >> 6, lane = t & 63, quad = lane >> 4, r16 = lane & 15;
  const int rt = w & 1, ch = w >> 1;
  f32x4 acc[4];
  f32x4 zz = {0.f, 0.f, 0.f, 0.f};
  acc[0] = zz; acc[1] = zz; acc[2] = zz; acc[3] = zz;
  for (int pair = 0; pair < 2; ++pair) {
    const float* A = pair ? A2 : A1;
    const short* W = pair ? W2 : W1;
    if (!A) break;
    if (pair) __syncthreads();
    {
      int row = t >> 3, seg = t & 7;
      const float* ap = &A[(size_t)(m0 + row) * D + seg * 16];
      float4 v0 = ld4(ap), v1 = ld4(ap + 4), v2 = ld4(ap + 8), v3 = ld4(ap + 12);
      bf16x8 w0 = {f2bf(v0.x), f2bf(v0.y), f2bf(v0.z), f2bf(v0.w),
                   f2bf(v1.x), f2bf(v1.y), f2bf(v1.z), f2bf(v1.w)};
      bf16x8 w1v = {f2bf(v2.x), f2bf(v2.y), f2bf(v2.z), f2bf(v2.w),
                    f2bf(v3.x), f2bf(v3.y), f2bf(v3.z), f2bf(v3.w)};
      *(bf16x8*)&As[row * 136 + seg * 16] = w0;
      *(bf16x8*)&As[row * 136 + seg * 16 + 8] = w1v;
    }
    __syncthreads();
    mfma_accum(As, W, rt, ch, quad, r16, acc);
  }
#pragma unroll
  for (int nt = 0; nt < 4; ++nt) {
    int col = ch * 64 + nt * 16 + r16;
    float bias = 0.f;
    if (b1) bias += b1[col];
    if (b2) bias += b2[col];
#pragma unroll
    for (int g = 0; g < 4; ++g) {
      int row = m0 + rt * 16 + quad * 4 + g;
      float v = acc[nt][g] + bias;
      if (Rres) v += Rres[(size_t)row * D + col];
      if (act) v = fmaxf(v, 0.f);
      C[(size_t)row * D + col] = v;
    }
  }
}

__global__ __launch_bounds__(256) void gemm_bf16_kernel(
    const float* A1, const short* W1, const float* b1,
    const float* A2, const short* W2, const float* b2,
    const float* Rres, float* C, int act) {
  __shared__ short As[32 * 136];
  gemm_core(A1, W1, b1, A2, W2, b2, Rres, C, act, blockIdx.x * 32, As);
}

// fused Q/K/V projections
__global__ __launch_bounds__(256) void qkv_kernel(
    const float* __restrict__ X, const float* __restrict__ seq,
    const short* __restrict__ Wq, const short* __restrict__ Wk, const short* __restrict__ Wv,
    const float* __restrict__ ipb, float* Qo, float* Ko, float* Vo) {
  __shared__ short As[32 * 136];
  int b = blockIdx.x;
  if (b < 256)
    gemm_core(X, Wq, ipb, nullptr, nullptr, nullptr, nullptr, Qo, 0, b * 32, As);
  else if (b < 320)
    gemm_core(seq, Wk, ipb + 128, nullptr, nullptr, nullptr, nullptr, Ko, 0, (b - 256) * 32, As);
  else
    gemm_core(seq, Wv, ipb + 256, nullptr, nullptr, nullptr, nullptr, Vo, 0, (b - 320) * 32, As);
}

// ---------------- out_proj GEMM with fused split-merge staging ----------------
__global__ __launch_bounds__(256) void gemm_op_kernel(
    const float* __restrict__ Osp, const float* __restrict__ lbuf,
    const short* __restrict__ W, const float* __restrict__ bias,
    const float* __restrict__ Rres, float* __restrict__ C, int N) {
  __shared__ short As[32 * 136];
  const int t = threadIdx.x;
  const int m0 = blockIdx.x * 32;
  const int w = t >> 6, lane = t & 63, quad = lane >> 4, r16 = lane & 15;
  const int rt = w & 1, ch = w >> 1;
  {
    int row = t >> 3, seg = t & 7;
    int grow = m0 + row;
    int h = seg >> 1;
    float l = lbuf[h * N + grow] + lbuf[(4 + h) * N + grow] +
              lbuf[(8 + h) * N + grow] + lbuf[(12 + h) * N + grow];
    float inv = 1.f / l;
    const float* p = &Osp[(size_t)grow * D + seg * 16];
    size_t st = (size_t)N * D;
    float acc16[16];
#pragma unroll
    for (int q = 0; q < 4; ++q) {
      float4 a = ld4(p + q * 4), b = ld4(p + st + q * 4),
             c = ld4(p + 2 * st + q * 4), d = ld4(p + 3 * st + q * 4);
      acc16[q * 4 + 0] = (a.x + b.x + c.x + d.x) * inv;
      acc16[q * 4 + 1] = (a.y + b.y + c.y + d.y) * inv;
      acc16[q * 4 + 2] = (a.z + b.z + c.z + d.z) * inv;
      acc16[q * 4 + 3] = (a.w + b.w + c.w + d.w) * inv;
    }
    bf16x8 w0 = {f2bf(acc16[0]), f2bf(acc16[1]), f2bf(acc16[2]), f2bf(acc16[3]),
                 f2bf(acc16[4]), f2bf(acc16[5]), f2bf(acc16[6]), f2bf(acc16[7])};
    bf16x8 w1v = {f2bf(acc16[8]), f2bf(acc16[9]), f2bf(acc16[10]), f2bf(acc16[11]),
                  f2bf(acc16[12]), f2bf(acc16[13]), f2bf(acc16[14]), f2bf(acc16[15])};
    *(bf16x8*)&As[row * 136 + seg * 16] = w0;
    *(bf16x8*)&As[row * 136 + seg * 16 + 8] = w1v;
  }
  __syncthreads();
  f32x4 acc[4];
  f32x4 zz = {0.f, 0.f, 0.f, 0.f};
  acc[0] = zz; acc[1] = zz; acc[2] = zz; acc[3] = zz;
  mfma_accum(As, W, rt, ch, quad, r16, acc);
#pragma unroll
  for (int nt = 0; nt < 4; ++nt) {
    int col = ch * 64 + nt * 16 + r16;
    float b = bias[col];
#pragma unroll
    for (int g = 0; g < 4; ++g) {
      int row = m0 + rt * 16 + quad * 4 + g;
      float v = acc[nt][g] + b + Rres[(size_t)row * D + col];
      C[(size_t)row * D + col] = v;
    }
  }
}

// ---------------- K/V prep: fp32 -> bf16, V transposed, per-head max |k|^2 ----------------
__global__ __launch_bounds__(256) void kv_prep_kernel(
    const float* __restrict__ KB, const float* __restrict__ VB,
    short* __restrict__ Kbf, short* __restrict__ Vt, int* __restrict__ MkhI, int S) {
  __shared__ short VtS[128 * 40];
  __shared__ float kn[128];
  const int t = threadIdx.x;
  const int s0 = blockIdx.x * 32;
  if (t < 128) kn[t] = 0.f;
  __syncthreads();
#pragma unroll
  for (int i = 0; i < 4; ++i) {
    int id = t + i * 256;
    int key = id >> 5, d4 = (id & 31) * 4;
    float4 kv = ld4(&KB[(size_t)(s0 + key) * D + d4]);
    bf16x4 kw = {f2bf(kv.x), f2bf(kv.y), f2bf(kv.z), f2bf(kv.w)};
    *(bf16x4*)&Kbf[(size_t)(s0 + key) * D + d4] = kw;
    float ss = kv.x * kv.x + kv.y * kv.y + kv.z * kv.z + kv.w * kv.w;
    atomicAdd(&kn[key * 4 + (d4 >> 5)], ss);
    float4 vv = ld4(&VB[(size_t)(s0 + key) * D + d4]);
    VtS[(d4 + 0) * 40 + key] = f2bf(vv.x);
    VtS[(d4 + 1) * 40 + key] = f2bf(vv.y);
    VtS[(d4 + 2) * 40 + key] = f2bf(vv.z);
    VtS[(d4 + 3) * 40 + key] = f2bf(vv.w);
  }
  __syncthreads();
  if (t < 128) {
    int key = t >> 2, h = t & 3;
    atomicMax(&MkhI[h], __float_as_int(kn[key * 4 + h]));
  }
  int dim = t >> 1, half = t & 1;
  bf16x8 v0 = *(bf16x8*)&VtS[dim * 40 + half * 16];
  bf16x8 v1 = *(bf16x8*)&VtS[dim * 40 + half * 16 + 8];
  *(bf16x8*)&Vt[(size_t)dim * S + s0 + half * 16] = v0;
  *(bf16x8*)&Vt[(size_t)dim * S + s0 + half * 16 + 8] = v1;
}

// ---------------- Q prep (scale folds 1/sqrt(32) * log2(e); scores in log2 domain) ----------------
__global__ __launch_bounds__(256) void q_prep_kernel(
    const float* __restrict__ Qf, const int* __restrict__ MkhI,
    short* __restrict__ Qbf, float* __restrict__ mrow, int N) {
  const int t = threadIdx.x;
  const int r = blockIdx.x * 16 + (t >> 4);
  const int l16 = t & 15;
  const float sc = 0.25503473f;   // (1/sqrt(32)) * log2(e)
  const float* qp = &Qf[(size_t)r * D + l16 * 8];
  float4 a = ld4(qp), b = ld4(qp + 4);
  a.x *= sc; a.y *= sc; a.z *= sc; a.w *= sc;
  b.x *= sc; b.y *= sc; b.z *= sc; b.w *= sc;
  bf16x8 w = {f2bf(a.x), f2bf(a.y), f2bf(a.z), f2bf(a.w),
              f2bf(b.x), f2bf(b.y), f2bf(b.z), f2bf(b.w)};
  *(bf16x8*)&Qbf[(size_t)r * D + l16 * 8] = w;
  float ss = a.x * a.x + a.y * a.y + a.z * a.z + a.w * a.w +
             b.x * b.x + b.y * b.y + b.z * b.z + b.w * b.w;
  ss += __shfl_xor(ss, 1);
  ss += __shfl_xor(ss, 2);
  if ((l16 & 3) == 0) {
    int h = l16 >> 2;
    float mk = __int_as_float(MkhI[h]);
    mrow[h * N + r] = sqrtf(ss) * sqrtf(fmaxf(mk, 0.f));   // log2-domain bound
  }
}

// ---------------- MFMA flash attention, fixed-shift softmax, split-S=4, no atomics ----------------
__global__ __launch_bounds__(64, 4) void flash_kernel(
    const short* __restrict__ Qbf, const short* __restrict__ Kbf, const short* __restrict__ Vt,
    const float* __restrict__ mrow, float* __restrict__ Osp, float* __restrict__ lbuf,
    int N, int S) {
  __shared__ short Ps[32 * 72];
  const int lane = threadIdx.x;
  const int quad = lane >> 4, r16 = lane & 15;
  const int n0 = blockIdx.x * 32;
  const int h = blockIdx.y;
  const int sp = blockIdx.z;
  float* O = Osp + (size_t)sp * N * D;

  bf16x8 aq[2];
  aq[0] = *(const bf16x8*)&Qbf[(size_t)(n0 + r16) * D + h * 32 + quad * 8];
  aq[1] = *(const bf16x8*)&Qbf[(size_t)(n0 + 16 + r16) * D + h * 32 + quad * 8];

  float msh[2][4];
#pragma unroll
  for (int rt = 0; rt < 2; ++rt)
#pragma unroll
    for (int g = 0; g < 4; ++g)
      msh[rt][g] = fminf(mrow[h * N + n0 + rt * 16 + quad * 4 + g], 57.7f);

  f32x4 o[2][2], lac[2];
  f32x4 zz = {0.f, 0.f, 0.f, 0.f};
  o[0][0] = zz; o[0][1] = zz; o[1][0] = zz; o[1][1] = zz;
  lac[0] = zz; lac[1] = zz;
  bf16x8 ones = {(short)0x3F80, (short)0x3F80, (short)0x3F80, (short)0x3F80,
                 (short)0x3F80, (short)0x3F80, (short)0x3F80, (short)0x3F80};

  const int span = S >> 2;
  const int c0 = sp * span;
  for (int c = c0; c < c0 + span; c += 64) {
    f32x4 s[2][4];
#pragma unroll
    for (int kt = 0; kt < 4; ++kt) {
      bf16x8 bk = *(const bf16x8*)&Kbf[(size_t)(c + kt * 16 + r16) * D + h * 32 + quad * 8];
      f32x4 z = {0.f, 0.f, 0.f, 0.f};
      s[0][kt] = __builtin_amdgcn_mfma_f32_16x16x32_bf16(aq[0], bk, z, 0, 0, 0);
      s[1][kt] = __builtin_amdgcn_mfma_f32_16x16x32_bf16(aq[1], bk, z, 0, 0, 0);
    }
#pragma unroll
    for (int rt = 0; rt < 2; ++rt)
#pragma unroll
      for (int kt = 0; kt < 4; ++kt)
#pragma unroll
        for (int g = 0; g < 4; ++g) {
          float p = exp2f(s[rt][kt][g] - msh[rt][g]);
          Ps[(rt * 16 + quad * 4 + g) * 72 + kt * 16 + r16] = f2bf(p);
        }
    // same-wave LDS round-trip (lgkmcnt only, no barrier)
#pragma unroll
    for (int rt = 0; rt < 2; ++rt)
#pragma unroll
      for (int kc = 0; kc < 2; ++kc) {
        bf16x8 ap = *(bf16x8*)&Ps[(rt * 16 + r16) * 72 + kc * 32 + quad * 8];
        lac[rt] = __builtin_amdgcn_mfma_f32_16x16x32_bf16(ap, ones, lac[rt], 0, 0, 0);
#pragma unroll
        for (int nt = 0; nt < 2; ++nt) {
          bf16x8 bv = *(const bf16x8*)&Vt[(size_t)(h * 32 + nt * 16 + r16) * S + c + kc * 32 + quad * 8];
          o[rt][nt] = __builtin_amdgcn_mfma_f32_16x16x32_bf16(ap, bv, o[rt][nt], 0, 0, 0);
        }
      }
  }
#pragma unroll
  for (int rt = 0; rt < 2; ++rt)
#pragma unroll
    for (int g = 0; g < 4; ++g) {
      int row = n0 + rt * 16 + quad * 4 + g;
#pragma unroll
      for (int nt = 0; nt < 2; ++nt)
        O[(size_t)row * D + h * 32 + nt * 16 + r16] = o[rt][nt][g];
      if (r16 == 0) lbuf[(sp * 4 + h) * N + row] = lac[rt][g];
    }
}

// ---------------- LayerNorm + L2 normalize (1 wave per row) ----------------
__global__ __launch_bounds__(64) void ln_l2_kernel(
    const float* __restrict__ X, const float* __restrict__ g, const float* __restrict__ b,
    float* __restrict__ out) {
  int n = blockIdx.x, t = threadIdx.x;
  float2 v = *(const float2*)&X[n * D + t * 2];
  float s = v.x + v.y;
  for (int off = 32; off; off >>= 1) s += __shfl_xor(s, off);
  float mu = s * (1.f / 128.f);
  float dx = v.x - mu, dy = v.y - mu;
  float q = dx * dx + dy * dy;
  for (int off = 32; off; off >>= 1) q += __shfl_xor(q, off);
  float rs = rsqrtf(q * (1.f / 128.f) + 1e-5f);
  float2 gg = *(const float2*)&g[t * 2];
  float2 bb = *(const float2*)&b[t * 2];
  float yx = dx * rs * gg.x + bb.x;
  float yy = dy * rs * gg.y + bb.y;
  float nn = yx * yx + yy * yy;
  for (int off = 32; off; off >>= 1) nn += __shfl_xor(nn, off);
  float inv = 1.f / fmaxf(sqrtf(nn), 1e-12f);
  float2 ov = {yx * inv, yy * inv};
  *(float2*)&out[n * D + t * 2] = ov;
}

// ---------------- MLP layer 2 + sigmoid ----------------
__global__ __launch_bounds__(256) void mlp2_kernel(
    const float* __restrict__ H, const float* __restrict__ w2, float* __restrict__ p, int M) {
  int row = blockIdx.x * 4 + (threadIdx.x >> 6);
  int lane = threadIdx.x & 63;
  if (row >= M) return;
  float2 h2 = *(const float2*)&H[row * D + lane * 2];
  float2 w = *(const float2*)&w2[lane * 2];
  float s = h2.x * w.x + h2.y * w.y;
  for (int off = 32; off; off >>= 1) s += __shfl_xor(s, off);
  if (lane == 0) p[row] = 1.f / (1.f + __expf(-s));
}

// ---------------- edge prediction ----------------
__global__ void pred_kernel(const float* __restrict__ p, const int* __restrict__ eli,
                            float* __restrict__ out, int K) {
  int i = blockIdx.x * blockDim.x + threadIdx.x;
  if (i < K) out[i] = p[eli[i]] * p[eli[K + i]];
}

extern "C" void kernel_launch(void* const* d_in, const int* in_sizes, int n_in,
                              void* d_out, int out_size, void* d_ws, size_t ws_size,
                              hipStream_t stream) {
  const float* x       = (const float*)d_in[0];
  const float* seq     = (const float*)d_in[1];
  const int* src       = (const int*)d_in[2];
  const int* dst       = (const int*)d_in[3];
  const int* eli       = (const int*)d_in[4];
  const float* skip_w0 = (const float*)d_in[5];
  const float* skip_b0 = (const float*)d_in[6];
  const float* msg_w0  = (const float*)d_in[7];
  const float* msg_b0  = (const float*)d_in[8];
  const float* skip_w1 = (const float*)d_in[9];
  const float* skip_b1 = (const float*)d_in[10];
  const float* msg_w1  = (const float*)d_in[11];
  const float* msg_b1  = (const float*)d_in[12];
  const float* ipw     = (const float*)d_in[13];
  const float* ipb     = (const float*)d_in[14];
  const float* opw     = (const float*)d_in[15];
  const float* opb     = (const float*)d_in[16];
  const float* ln_g    = (const float*)d_in[17];
  const float* ln_b    = (const float*)d_in[18];
  const float* w1      = (const float*)d_in[19];
  const float* w2      = (const float*)d_in[20];

  const int N  = in_sizes[0] / D;   // 8192
  const int S  = in_sizes[1] / D;   // 2048
  const int E  = in_sizes[2];       // 524288
  const int Kp = in_sizes[4] / 2;   // 100000

  float* ws    = (float*)d_ws;
  float* Bagg  = ws;                        // agg scratch
  float* B1    = Bagg + (size_t)N * D;      // gcn1 out / pre-LN
  float* B2    = B1 + (size_t)N * D;        // gcn2 out (residual)
  float* B3    = B2 + (size_t)N * D;        // Q fp32 / mlp hidden
  float* KB    = B3 + (size_t)N * D;
  float* VB    = KB + (size_t)S * D;
  float* Osp   = VB + (size_t)S * D;        // 4 * N * D split outputs
  short* Qbf   = (short*)(Osp + 4 * (size_t)N * D);
  short* Kbf   = Qbf + (size_t)N * D;
  short* Vt    = Kbf + (size_t)S * D;
  short* Wbf   = Vt + (size_t)D * S;             // 9 * 16384
  float* mrow  = (float*)(Wbf + 9 * 16384);      // 4*N
  float* lbuf  = mrow + 4 * (size_t)N;           // 16*N
  float* dinv  = lbuf + 16 * (size_t)N;
  float* pbuf  = dinv + N;
  int*   MkhI  = (int*)(pbuf + N);               // 4
  int* deg     = MkhI + 4;                       // N
  int* row_ptr = deg + N;                        // N+1
  int* csr_src = row_ptr + (N + 1);              // E
  int* histd   = csr_src + E;                    // HB*8192
  int* hists   = histd + HB * 8192;              // HB*8192
  int* base_arr= hists + HB * 8192;              // HB*8192

  float* pred_out = (float*)d_out;
  float* emb_out  = pred_out + Kp;

  const short* w_skip0 = Wbf + 0 * 16384;
  const short* w_msg0  = Wbf + 1 * 16384;
  const short* w_skip1 = Wbf + 2 * 16384;
  const short* w_msg1  = Wbf + 3 * 16384;
  const short* w_q     = Wbf + 4 * 16384;
  const short* w_k     = Wbf + 5 * 16384;
  const short* w_v     = Wbf + 6 * 16384;
  const short* w_op    = Wbf + 7 * 16384;
  const short* w_m1    = Wbf + 8 * 16384;

  hipMemsetAsync(MkhI, 0, 4 * sizeof(int), stream);

  WSrc wsrc;
  wsrc.p[0] = skip_w0; wsrc.p[1] = msg_w0; wsrc.p[2] = skip_w1; wsrc.p[3] = msg_w1;
  wsrc.p[4] = ipw; wsrc.p[5] = ipw + D * D; wsrc.p[6] = ipw + 2 * D * D;
  wsrc.p[7] = opw; wsrc.p[8] = w1;
  dim3 wgrid(16, 9);
  wprep_kernel<<<wgrid, 256, 0, stream>>>(wsrc, (short*)Wbf);

  // atomic-free CSR build
  hist_kernel<<<HB, 256, 0, stream>>>(src, dst, histd, hists, E);
  colsum_kernel<<<N / 256, 256, 0, stream>>>(histd, hists, deg, dinv);
  scan8k_kernel<<<1, 1024, 0, stream>>>(deg, row_ptr, N);
  basegen_kernel<<<N / 256, 256, 0, stream>>>(histd, row_ptr, base_arr);
  scatter2_kernel<<<HB, 256, 0, stream>>>(src, dst, base_arr, csr_src, E);

  // GCN layers (dual-pair MFMA GEMMs)
  agg_kernel<<<N, 128, 0, stream>>>(x, dinv, row_ptr, csr_src, Bagg);
  gemm_bf16_kernel<<<N / 32, 256, 0, stream>>>(Bagg, w_msg0, msg_b0, x, w_skip0, skip_b0, nullptr, B1, 0);
  agg_kernel<<<N, 128, 0, stream>>>(B1, dinv, row_ptr, csr_src, Bagg);
  gemm_bf16_kernel<<<N / 32, 256, 0, stream>>>(Bagg, w_msg1, msg_b1, B1, w_skip1, skip_b1, nullptr, B2, 0);

  // fused Q/K/V projections
  qkv_kernel<<<N / 32 + 2 * (S / 32), 256, 0, stream>>>(B2, seq, w_q, w_k, w_v, ipb, B3, KB, VB);

  // bf16 prep + shift bounds
  kv_prep_kernel<<<S / 32, 256, 0, stream>>>(KB, VB, Kbf, Vt, MkhI, S);
  q_prep_kernel<<<N / 16, 256, 0, stream>>>(B3, MkhI, Qbf, mrow, N);

  // attention: split-S=4, plain stores, merge fused into out_proj GEMM
  dim3 fgrid(N / 32, 4, 4);
  flash_kernel<<<fgrid, 64, 0, stream>>>(Qbf, Kbf, Vt, mrow, Osp, lbuf, N, S);
  gemm_op_kernel<<<N / 32, 256, 0, stream>>>(Osp, lbuf, w_op, opb, B2, B1, N);

  // LN+L2 -> emb; MLP; prediction
  ln_l2_kernel<<<N, 64, 0, stream>>>(B1, ln_g, ln_b, emb_out);
  gemm_bf16_kernel<<<N / 32, 256, 0, stream>>>(emb_out, w_m1, nullptr, nullptr, nullptr, nullptr, nullptr, B3, 1);
  mlp2_kernel<<<N / 4, 256, 0, stream>>>(B3, w2, pbuf, N);
  pred_kernel<<<(Kp + 255) / 256, 256, 0, stream>>>(pbuf, eli, pred_out, Kp);
}

// Round 6
// 238.436 us; speedup vs baseline: 2.5271x; 1.2384x over previous
//
#include <hip/hip_runtime.h>
#include <math.h>

#define D 128
#define HB 128     // histogram blocks
#define FA_PS 88   // flash P stride (shorts): 176B = 16B-multiple, low-conflict

typedef short bf16x4 __attribute__((ext_vector_type(4)));
typedef short bf16x8 __attribute__((ext_vector_type(8)));
typedef float f32x4 __attribute__((ext_vector_type(4)));

__device__ __forceinline__ float4 ld4(const float* p) { return *(const float4*)p; }

__device__ __forceinline__ short f2bf_r(float f) {   // round-half-up (ties ~never exact)
  return (short)((__float_as_uint(f) + 0x8000u) >> 16);
}
__device__ __forceinline__ float bf2f(short s) {
  return __uint_as_float(((unsigned)(unsigned short)s) << 16);
}
__device__ __forceinline__ unsigned pack_bf2(float a, float b) {  // [bf(a),bf(b)] as b32
  unsigned ua = __float_as_uint(a) + 0x8000u;
  unsigned ub = __float_as_uint(b) + 0x8000u;
  return __builtin_amdgcn_perm(ub, ua, 0x07060302);
}

// ---------------- prep0: 9 weight matrices fp32->bf16 + x -> bf16 ----------------
struct WSrc { const float* p[9]; };
__global__ __launch_bounds__(256) void prep0_kernel(WSrc ws, short* __restrict__ Wbf,
                                                    const float* __restrict__ x,
                                                    short* __restrict__ xbf) {
  int b = blockIdx.x, t = threadIdx.x;
  if (b < 144) {
    int m = b >> 4, blk = b & 15;
    int i = (blk * 256 + t) * 4;
    float4 v = ld4(ws.p[m] + i);
    bf16x4 o = {f2bf_r(v.x), f2bf_r(v.y), f2bf_r(v.z), f2bf_r(v.w)};
    *(bf16x4*)&Wbf[m * 16384 + i] = o;
  } else {
    int i = ((b - 144) * 256 + t) * 4;
    float4 v = ld4(x + i);
    bf16x4 o = {f2bf_r(v.x), f2bf_r(v.y), f2bf_r(v.z), f2bf_r(v.w)};
    *(bf16x4*)&xbf[i] = o;
  }
}

// ---------------- CSR build, atomic-free (LDS-privatized histograms) ----------------
__global__ __launch_bounds__(256) void hist_kernel(
    const int* __restrict__ src, const int* __restrict__ dst,
    int* __restrict__ histd, int* __restrict__ hists, int E) {
  __shared__ int hd[8192];
  __shared__ int hs[8192];
  int t = threadIdx.x;
  for (int i = t; i < 8192; i += 256) { hd[i] = 0; hs[i] = 0; }
  __syncthreads();
  int per = E / HB;
  int b0 = blockIdx.x * per;
  for (int j = 0; j < per; j += 256) {
    int i = b0 + j + t;
    atomicAdd(&hd[dst[i]], 1);
    atomicAdd(&hs[src[i]], 1);
  }
  __syncthreads();
  for (int i = t; i < 8192; i += 256) {
    histd[blockIdx.x * 8192 + i] = hd[i];
    hists[blockIdx.x * 8192 + i] = hs[i];
  }
}

__global__ __launch_bounds__(256) void colsum_kernel(
    const int* __restrict__ histd, const int* __restrict__ hists,
    int* __restrict__ deg, float* __restrict__ dinv) {
  int v = blockIdx.x * 256 + threadIdx.x;
  int sd = 0, ss = 0;
  for (int b = 0; b < HB; ++b) { sd += histd[b * 8192 + v]; ss += hists[b * 8192 + v]; }
  deg[v] = sd;
  dinv[v] = ss > 0 ? rsqrtf((float)ss) : 0.f;
}

__global__ __launch_bounds__(1024) void scan8k_kernel(
    const int* __restrict__ deg, int* __restrict__ row_ptr, int N) {
  __shared__ int wtot[16];
  int t = threadIdx.x;
  int lane = t & 63, wv = t >> 6;
  int v0 = t * 8;
  int x[8]; int s = 0;
#pragma unroll
  for (int j = 0; j < 8; ++j) { x[j] = s; s += deg[v0 + j]; }
  int incl = s;
  for (int off = 1; off < 64; off <<= 1) {
    int y = __shfl_up(incl, off);
    if (lane >= off) incl += y;
  }
  if (lane == 63) wtot[wv] = incl;
  __syncthreads();
  if (t == 0) { int run = 0; for (int i = 0; i < 16; ++i) { int v = wtot[i]; wtot[i] = run; run += v; } }
  __syncthreads();
  int base = wtot[wv] + (incl - s);
#pragma unroll
  for (int j = 0; j < 8; ++j) row_ptr[v0 + j] = base + x[j];
  if (t == 1023) row_ptr[N] = base + s;
}

__global__ __launch_bounds__(256) void basegen_kernel(
    const int* __restrict__ histd, const int* __restrict__ row_ptr,
    int* __restrict__ base_arr) {
  int v = blockIdx.x * 256 + threadIdx.x;
  int run = row_ptr[v];
  for (int b = 0; b < HB; ++b) { base_arr[b * 8192 + v] = run; run += histd[b * 8192 + v]; }
}

__global__ __launch_bounds__(256) void scatter2_kernel(
    const int* __restrict__ src, const int* __restrict__ dst,
    const int* __restrict__ base_arr, int* __restrict__ csr_src, int E) {
  __shared__ int lh[8192];
  int t = threadIdx.x;
  for (int i = t; i < 8192; i += 256) lh[i] = 0;
  __syncthreads();
  int per = E / HB;
  int b0 = blockIdx.x * per;
  const int* __restrict__ bb = &base_arr[blockIdx.x * 8192];
  for (int j = 0; j < per; j += 256) {
    int i = b0 + j + t;
    int v = dst[i];
    int r = atomicAdd(&lh[v], 1);
    csr_src[bb[v] + r] = src[i];
  }
}

// ---------------- GCN aggregation: bf16 gather, bf16 out; 8 edges in flight ----------------
__global__ __launch_bounds__(128) void agg_kernel(
    const short* __restrict__ fbf, const float* __restrict__ dinv,
    const int* __restrict__ row_ptr, const int* __restrict__ csr_src,
    short* __restrict__ outbf) {
  __shared__ int idx[128];
  __shared__ float dv[128];
  __shared__ float red[8][128];
  int n = blockIdx.x, t = threadIdx.x;
  int grp = t >> 4, l16 = t & 15;
  int beg = row_ptr[n], end = row_ptr[n + 1];
  float a0[8] = {}, a1[8] = {};
  for (int c = beg; c < end; c += 128) {
    int j = c + t;
    if (j < end) { int s = csr_src[j]; idx[t] = s; dv[t] = dinv[s]; }
    __syncthreads();
    int cnt = min(128, end - c);
    int e = grp;
    for (; e + 8 < cnt; e += 16) {
      bf16x8 w0 = *(const bf16x8*)&fbf[(size_t)idx[e] * D + l16 * 8];
      bf16x8 w1 = *(const bf16x8*)&fbf[(size_t)idx[e + 8] * D + l16 * 8];
      float wt0 = dv[e], wt1 = dv[e + 8];
#pragma unroll
      for (int k = 0; k < 8; ++k) {
        a0[k] += bf2f(w0[k]) * wt0;
        a1[k] += bf2f(w1[k]) * wt1;
      }
    }
    for (; e < cnt; e += 8) {
      bf16x8 w0 = *(const bf16x8*)&fbf[(size_t)idx[e] * D + l16 * 8];
      float wt0 = dv[e];
#pragma unroll
      for (int k = 0; k < 8; ++k) a0[k] += bf2f(w0[k]) * wt0;
    }
    __syncthreads();
  }
#pragma unroll
  for (int k = 0; k < 8; ++k) a0[k] += a1[k];
  *(float4*)&red[grp][l16 * 8] = *(float4*)&a0[0];
  *(float4*)&red[grp][l16 * 8 + 4] = *(float4*)&a0[4];
  __syncthreads();
  if (t < 32) {
    int d0 = t * 4;
    float o[4] = {};
#pragma unroll
    for (int g = 0; g < 8; ++g) {
      o[0] += red[g][d0]; o[1] += red[g][d0 + 1];
      o[2] += red[g][d0 + 2]; o[3] += red[g][d0 + 3];
    }
    float w = dinv[n];
    bf16x4 ov = {f2bf_r(o[0] * w), f2bf_r(o[1] * w), f2bf_r(o[2] * w), f2bf_r(o[3] * w)};
    *(bf16x4*)&outbf[(size_t)n * D + d0] = ov;
  }
}

// ---------------- MFMA helpers ----------------
__device__ __forceinline__ void mfma_accum(const short* As, const short* __restrict__ W,
                                           int rt, int ch, int quad, int r16, f32x4* acc) {
#pragma unroll
  for (int ks = 0; ks < 4; ++ks) {
    bf16x8 af = *(bf16x8*)&As[(rt * 16 + r16) * 136 + ks * 32 + quad * 8];
#pragma unroll
    for (int nt = 0; nt < 4; ++nt) {
      bf16x8 bw = *(const bf16x8*)&W[(size_t)(ch * 64 + nt * 16 + r16) * D + ks * 32 + quad * 8];
      acc[nt] = __builtin_amdgcn_mfma_f32_16x16x32_bf16(af, bw, acc[nt], 0, 0, 0);
    }
  }
}

__device__ __forceinline__ void stage_A_f32(const float* __restrict__ A, int m0, short* As) {
  int row = threadIdx.x >> 3, seg = threadIdx.x & 7;
  const float* ap = &A[(size_t)(m0 + row) * D + seg * 16];
  float4 v0 = ld4(ap), v1 = ld4(ap + 4), v2 = ld4(ap + 8), v3 = ld4(ap + 12);
  bf16x8 w0 = {f2bf_r(v0.x), f2bf_r(v0.y), f2bf_r(v0.z), f2bf_r(v0.w),
               f2bf_r(v1.x), f2bf_r(v1.y), f2bf_r(v1.z), f2bf_r(v1.w)};
  bf16x8 w1 = {f2bf_r(v2.x), f2bf_r(v2.y), f2bf_r(v2.z), f2bf_r(v2.w),
               f2bf_r(v3.x), f2bf_r(v3.y), f2bf_r(v3.z), f2bf_r(v3.w)};
  *(bf16x8*)&As[row * 136 + seg * 16] = w0;
  *(bf16x8*)&As[row * 136 + seg * 16 + 8] = w1;
}

__device__ __forceinline__ void stage_A_bf16(const short* __restrict__ A, int m0, short* As) {
  int row = threadIdx.x >> 3, seg = threadIdx.x & 7;
  const short* ap = &A[(size_t)(m0 + row) * D + seg * 16];
  bf16x8 a0 = *(const bf16x8*)ap;
  bf16x8 a1 = *(const bf16x8*)(ap + 8);
  *(bf16x8*)&As[row * 136 + seg * 16] = a0;
  *(bf16x8*)&As[row * 136 + seg * 16 + 8] = a1;
}

// ---------------- GCN dual GEMM: C = A1@W1^T + A2@W2^T + b1 + b2 (bf16 A, bf16/f32 out) ----------------
__global__ __launch_bounds__(256) void gemm_gcn_kernel(
    const short* __restrict__ A1, const short* __restrict__ W1, const float* __restrict__ b1,
    const short* __restrict__ A2, const short* __restrict__ W2, const float* __restrict__ b2,
    short* __restrict__ Cbf, float* __restrict__ Cf) {
  __shared__ short As[32 * 136];
  const int t = threadIdx.x;
  const int m0 = blockIdx.x * 32;
  const int w = t >> 6, lane = t & 63, quad = lane >> 4, r16 = lane & 15;
  const int rt = w & 1, ch = w >> 1;
  f32x4 acc[4];
  f32x4 zz = {0.f, 0.f, 0.f, 0.f};
  acc[0] = zz; acc[1] = zz; acc[2] = zz; acc[3] = zz;
  stage_A_bf16(A1, m0, As);
  __syncthreads();
  mfma_accum(As, W1, rt, ch, quad, r16, acc);
  __syncthreads();
  stage_A_bf16(A2, m0, As);
  __syncthreads();
  mfma_accum(As, W2, rt, ch, quad, r16, acc);
#pragma unroll
  for (int nt = 0; nt < 4; ++nt) {
    int col = ch * 64 + nt * 16 + r16;
    float bias = b1[col] + b2[col];
#pragma unroll
    for (int g = 0; g < 4; ++g) {
      int row = m0 + rt * 16 + quad * 4 + g;
      float v = acc[nt][g] + bias;
      if (Cbf) Cbf[(size_t)row * D + col] = f2bf_r(v);
      if (Cf) Cf[(size_t)row * D + col] = v;
    }
  }
}

// ---------------- fused QKV projections with prep epilogues ----------------
// blocks [0,256): Q over B2 -> Qbf (scaled bf16) + qn row-head norms
// blocks [256,320): K over seq -> Kbf bf16 + MkhI per-head max |k|^2
// blocks [320,384): V over seq -> Vt bf16, [dim][key] with per-64 key' permutation
__global__ __launch_bounds__(256) void qkv_kernel(
    const float* __restrict__ B2, const float* __restrict__ seq,
    const short* __restrict__ Wq, const short* __restrict__ Wk, const short* __restrict__ Wv,
    const float* __restrict__ ipb,
    short* __restrict__ Qbf, float* __restrict__ qn,
    short* __restrict__ Kbf, int* __restrict__ MkhI,
    short* __restrict__ Vt, int N, int S) {
  __shared__ short As[32 * 136];
  __shared__ int lmax[4];
  const int t = threadIdx.x;
  const int b = blockIdx.x;
  const int w = t >> 6, lane = t & 63, quad = lane >> 4, r16 = lane & 15;
  const int rt = w & 1, ch = w >> 1;
  if (t < 4) lmax[t] = 0;
  f32x4 acc[4];
  f32x4 zz = {0.f, 0.f, 0.f, 0.f};
  acc[0] = zz; acc[1] = zz; acc[2] = zz; acc[3] = zz;
  const float SC = 0.25503473f;   // (1/sqrt(32)) * log2(e)

  if (b < 256) {
    int m0 = b * 32;
    stage_A_f32(B2, m0, As);
    __syncthreads();
    mfma_accum(As, Wq, rt, ch, quad, r16, acc);
    float pq[4][2] = {};
#pragma unroll
    for (int nt = 0; nt < 4; ++nt) {
      int col = ch * 64 + nt * 16 + r16;
      float bias = ipb[col];
      int p = nt >> 1;
#pragma unroll
      for (int g = 0; g < 4; ++g) {
        int row = m0 + rt * 16 + quad * 4 + g;
        float vs = (acc[nt][g] + bias) * SC;
        Qbf[(size_t)row * D + col] = f2bf_r(vs);
        pq[g][p] += vs * vs;
      }
    }
#pragma unroll
    for (int mask = 1; mask < 16; mask <<= 1)
#pragma unroll
      for (int g = 0; g < 4; ++g) {
        pq[g][0] += __shfl_xor(pq[g][0], mask);
        pq[g][1] += __shfl_xor(pq[g][1], mask);
      }
    if (r16 == 0) {
#pragma unroll
      for (int g = 0; g < 4; ++g) {
        int row = m0 + rt * 16 + quad * 4 + g;
        qn[(ch * 2 + 0) * N + row] = sqrtf(pq[g][0]);
        qn[(ch * 2 + 1) * N + row] = sqrtf(pq[g][1]);
      }
    }
  } else if (b < 320) {
    int m0 = (b - 256) * 32;
    stage_A_f32(seq, m0, As);
    __syncthreads();
    mfma_accum(As, Wk, rt, ch, quad, r16, acc);
    float pk[4][2] = {};
#pragma unroll
    for (int nt = 0; nt < 4; ++nt) {
      int col = ch * 64 + nt * 16 + r16;
      float bias = ipb[128 + col];
      int p = nt >> 1;
#pragma unroll
      for (int g = 0; g < 4; ++g) {
        int key = m0 + rt * 16 + quad * 4 + g;
        float v = acc[nt][g] + bias;
        Kbf[(size_t)key * D + col] = f2bf_r(v);
        pk[g][p] += v * v;
      }
    }
#pragma unroll
    for (int mask = 1; mask < 16; mask <<= 1)
#pragma unroll
      for (int g = 0; g < 4; ++g) {
        pk[g][0] += __shfl_xor(pk[g][0], mask);
        pk[g][1] += __shfl_xor(pk[g][1], mask);
      }
    if (r16 == 0) {
#pragma unroll
      for (int g = 0; g < 4; ++g) {
        atomicMax(&lmax[ch * 2 + 0], __float_as_int(pk[g][0]));
        atomicMax(&lmax[ch * 2 + 1], __float_as_int(pk[g][1]));
      }
    }
    __syncthreads();
    if (t < 4) atomicMax(&MkhI[t], lmax[t]);
  } else {
    int m0 = (b - 320) * 32;
    stage_A_f32(seq, m0, As);
    __syncthreads();
    mfma_accum(As, Wv, rt, ch, quad, r16, acc);
#pragma unroll
    for (int nt = 0; nt < 4; ++nt) {
      int dim = ch * 64 + nt * 16 + r16;
      float bias = ipb[256 + dim];
#pragma unroll
      for (int g = 0; g < 4; ++g) {
        int s = m0 + rt * 16 + quad * 4 + g;
        int local = s & 63;
        int kp = (local & 15) * 4 + (local >> 4);     // key' permutation
        int gcol = (s & ~63) + kp;
        Vt[(size_t)dim * S + gcol] = f2bf_r(acc[nt][g] + bias);
      }
    }
  }
}

// ---------------- MFMA flash attention: fixed-shift (log2), split-S=4, permuted P ----------------
__global__ __launch_bounds__(64, 4) void flash_kernel(
    const short* __restrict__ Qbf, const short* __restrict__ Kbf, const short* __restrict__ Vt,
    const float* __restrict__ qn, const int* __restrict__ MkhI,
    float* __restrict__ Osp, float* __restrict__ lbuf, int N, int S) {
  __shared__ short Ps[32 * FA_PS];
  const int lane = threadIdx.x;
  const int quad = lane >> 4, r16 = lane & 15;
  const int n0 = blockIdx.x * 32;
  const int h = blockIdx.y;
  const int sp = blockIdx.z;
  float* O = Osp + (size_t)sp * N * D;

  bf16x8 aq[2];
  aq[0] = *(const bf16x8*)&Qbf[(size_t)(n0 + r16) * D + h * 32 + quad * 8];
  aq[1] = *(const bf16x8*)&Qbf[(size_t)(n0 + 16 + r16) * D + h * 32 + quad * 8];

  float sqm = sqrtf(fmaxf(__int_as_float(MkhI[h]), 0.f));
  float msh[2][4];
#pragma unroll
  for (int rt = 0; rt < 2; ++rt)
#pragma unroll
    for (int g = 0; g < 4; ++g)
      msh[rt][g] = fminf(qn[h * N + n0 + rt * 16 + quad * 4 + g] * sqm, 57.7f);

  f32x4 o[2][2], lac[2];
  f32x4 zz = {0.f, 0.f, 0.f, 0.f};
  o[0][0] = zz; o[0][1] = zz; o[1][0] = zz; o[1][1] = zz;
  lac[0] = zz; lac[1] = zz;
  bf16x8 ones = {(short)0x3F80, (short)0x3F80, (short)0x3F80, (short)0x3F80,
                 (short)0x3F80, (short)0x3F80, (short)0x3F80, (short)0x3F80};

  const int span = S >> 2;
  const int c0 = sp * span;
  for (int c = c0; c < c0 + span; c += 64) {
    f32x4 s[2][4];
#pragma unroll
    for (int kt = 0; kt < 4; ++kt) {
      bf16x8 bk = *(const bf16x8*)&Kbf[(size_t)(c + kt * 16 + r16) * D + h * 32 + quad * 8];
      f32x4 z = {0.f, 0.f, 0.f, 0.f};
      s[0][kt] = __builtin_amdgcn_mfma_f32_16x16x32_bf16(aq[0], bk, z, 0, 0, 0);
      s[1][kt] = __builtin_amdgcn_mfma_f32_16x16x32_bf16(aq[1], bk, z, 0, 0, 0);
    }
    // exp2 + pack pairs + b64 LDS store at Ps[row][r16*4 + kt] (key' = r16*4+kt)
#pragma unroll
    for (int rt = 0; rt < 2; ++rt)
#pragma unroll
      for (int g = 0; g < 4; ++g) {
        float m = msh[rt][g];
        float p0 = exp2f(s[rt][0][g] - m);
        float p1 = exp2f(s[rt][1][g] - m);
        float p2 = exp2f(s[rt][2][g] - m);
        float p3 = exp2f(s[rt][3][g] - m);
        uint2 uv = {pack_bf2(p0, p1), pack_bf2(p2, p3)};
        *(uint2*)&Ps[(rt * 16 + quad * 4 + g) * FA_PS + r16 * 4] = uv;
      }
    // PV over permuted keys: Vt columns match key' ordering
    bf16x8 bv[2][2];
#pragma unroll
    for (int kc = 0; kc < 2; ++kc)
#pragma unroll
      for (int nt = 0; nt < 2; ++nt)
        bv[kc][nt] = *(const bf16x8*)&Vt[(size_t)(h * 32 + nt * 16 + r16) * S + c + kc * 32 + quad * 8];
#pragma unroll
    for (int rt = 0; rt < 2; ++rt)
#pragma unroll
      for (int kc = 0; kc < 2; ++kc) {
        bf16x8 ap = *(bf16x8*)&Ps[(rt * 16 + r16) * FA_PS + kc * 32 + quad * 8];
        lac[rt] = __builtin_amdgcn_mfma_f32_16x16x32_bf16(ap, ones, lac[rt], 0, 0, 0);
#pragma unroll
        for (int nt = 0; nt < 2; ++nt)
          o[rt][nt] = __builtin_amdgcn_mfma_f32_16x16x32_bf16(ap, bv[kc][nt], o[rt][nt], 0, 0, 0);
      }
  }
#pragma unroll
  for (int rt = 0; rt < 2; ++rt)
#pragma unroll
    for (int g = 0; g < 4; ++g) {
      int row = n0 + rt * 16 + quad * 4 + g;
#pragma unroll
      for (int nt = 0; nt < 2; ++nt)
        O[(size_t)row * D + h * 32 + nt * 16 + r16] = o[rt][nt][g];
      if (r16 == 0) lbuf[(sp * 4 + h) * N + row] = lac[rt][g];
    }
}

// ---------------- out_proj GEMM: fused split-merge staging + residual + LN + L2 ----------------
__global__ __launch_bounds__(256) void gemm_op_kernel(
    const float* __restrict__ Osp, const float* __restrict__ lbuf,
    const short* __restrict__ W, const float* __restrict__ bias,
    const float* __restrict__ Rres, const float* __restrict__ ln_g,
    const float* __restrict__ ln_b, float* __restrict__ emb, int N) {
  __shared__ short As[32 * 136];
  __shared__ float Cs[32 * 132];
  const int t = threadIdx.x;
  const int m0 = blockIdx.x * 32;
  const int w = t >> 6, lane = t & 63, quad = lane >> 4, r16 = lane & 15;
  const int rt = w & 1, ch = w >> 1;
  {
    int row = t >> 3, seg = t & 7;
    int grow = m0 + row;
    int hh = seg >> 1;
    float l = lbuf[hh * N + grow] + lbuf[(4 + hh) * N + grow] +
              lbuf[(8 + hh) * N + grow] + lbuf[(12 + hh) * N + grow];
    float inv = 1.f / l;
    const float* p = &Osp[(size_t)grow * D + seg * 16];
    size_t st = (size_t)N * D;
    float a16[16];
#pragma unroll
    for (int q = 0; q < 4; ++q) {
      float4 a = ld4(p + q * 4), b = ld4(p + st + q * 4),
             c = ld4(p + 2 * st + q * 4), d = ld4(p + 3 * st + q * 4);
      a16[q * 4 + 0] = (a.x + b.x + c.x + d.x) * inv;
      a16[q * 4 + 1] = (a.y + b.y + c.y + d.y) * inv;
      a16[q * 4 + 2] = (a.z + b.z + c.z + d.z) * inv;
      a16[q * 4 + 3] = (a.w + b.w + c.w + d.w) * inv;
    }
    bf16x8 w0 = {f2bf_r(a16[0]), f2bf_r(a16[1]), f2bf_r(a16[2]), f2bf_r(a16[3]),
                 f2bf_r(a16[4]), f2bf_r(a16[5]), f2bf_r(a16[6]), f2bf_r(a16[7])};
    bf16x8 w1 = {f2bf_r(a16[8]), f2bf_r(a16[9]), f2bf_r(a16[10]), f2bf_r(a16[11]),
                 f2bf_r(a16[12]), f2bf_r(a16[13]), f2bf_r(a16[14]), f2bf_r(a16[15])};
    *(bf16x8*)&As[row * 136 + seg * 16] = w0;
    *(bf16x8*)&As[row * 136 + seg * 16 + 8] = w1;
  }
  __syncthreads();
  f32x4 acc[4];
  f32x4 zz = {0.f, 0.f, 0.f, 0.f};
  acc[0] = zz; acc[1] = zz; acc[2] = zz; acc[3] = zz;
  mfma_accum(As, W, rt, ch, quad, r16, acc);
#pragma unroll
  for (int nt = 0; nt < 4; ++nt) {
    int col = ch * 64 + nt * 16 + r16;
    float bs = bias[col];
#pragma unroll
    for (int g = 0; g < 4; ++g) {
      int lr = rt * 16 + quad * 4 + g;
      Cs[lr * 132 + col] = acc[nt][g] + bs + Rres[(size_t)(m0 + lr) * D + col];
    }
  }
  __syncthreads();
  // LN + L2: 8 threads per row
  {
    int row = t >> 3, seg = t & 7;
    float xv[16];
#pragma unroll
    for (int q = 0; q < 4; ++q) {
      f32x4 v = *(f32x4*)&Cs[row * 132 + seg * 16 + q * 4];
      xv[q * 4] = v[0]; xv[q * 4 + 1] = v[1]; xv[q * 4 + 2] = v[2]; xv[q * 4 + 3] = v[3];
    }
    float s = 0.f, sq = 0.f;
#pragma unroll
    for (int k = 0; k < 16; ++k) { s += xv[k]; sq += xv[k] * xv[k]; }
#pragma unroll
    for (int mask = 1; mask < 8; mask <<= 1) { s += __shfl_xor(s, mask); sq += __shfl_xor(sq, mask); }
    float mu = s * (1.f / 128.f);
    float var = fmaxf(sq * (1.f / 128.f) - mu * mu, 0.f);
    float rs = rsqrtf(var + 1e-5f);
    float yv[16], nn = 0.f;
#pragma unroll
    for (int q = 0; q < 4; ++q) {
      float4 gg = ld4(&ln_g[seg * 16 + q * 4]);
      float4 bb = ld4(&ln_b[seg * 16 + q * 4]);
      float y0 = (xv[q * 4] - mu) * rs * gg.x + bb.x;
      float y1 = (xv[q * 4 + 1] - mu) * rs * gg.y + bb.y;
      float y2 = (xv[q * 4 + 2] - mu) * rs * gg.z + bb.z;
      float y3 = (xv[q * 4 + 3] - mu) * rs * gg.w + bb.w;
      yv[q * 4] = y0; yv[q * 4 + 1] = y1; yv[q * 4 + 2] = y2; yv[q * 4 + 3] = y3;
      nn += y0 * y0 + y1 * y1 + y2 * y2 + y3 * y3;
    }
#pragma unroll
    for (int mask = 1; mask < 8; mask <<= 1) nn += __shfl_xor(nn, mask);
    float inv = 1.f / fmaxf(sqrtf(nn), 1e-12f);
#pragma unroll
    for (int q = 0; q < 4; ++q) {
      float4 ov = {yv[q * 4] * inv, yv[q * 4 + 1] * inv, yv[q * 4 + 2] * inv, yv[q * 4 + 3] * inv};
      *(float4*)&emb[(size_t)(m0 + row) * D + seg * 16 + q * 4] = ov;
    }
  }
}

// ---------------- MLP GEMM: hidden=relu(emb@w1^T) fused with p=sigmoid(hidden.w2) ----------------
__global__ __launch_bounds__(256) void gemm_mlp_kernel(
    const float* __restrict__ emb, const short* __restrict__ W,
    const float* __restrict__ w2, float* __restrict__ pbuf) {
  __shared__ short As[32 * 136];
  __shared__ float part[32][2];
  const int t = threadIdx.x;
  const int m0 = blockIdx.x * 32;
  const int w = t >> 6, lane = t & 63, quad = lane >> 4, r16 = lane & 15;
  const int rt = w & 1, ch = w >> 1;
  stage_A_f32(emb, m0, As);
  __syncthreads();
  f32x4 acc[4];
  f32x4 zz = {0.f, 0.f, 0.f, 0.f};
  acc[0] = zz; acc[1] = zz; acc[2] = zz; acc[3] = zz;
  mfma_accum(As, W, rt, ch, quad, r16, acc);
  float pg[4] = {};
#pragma unroll
  for (int nt = 0; nt < 4; ++nt) {
    float wv = w2[ch * 64 + nt * 16 + r16];
#pragma unroll
    for (int g = 0; g < 4; ++g) pg[g] += fmaxf(acc[nt][g], 0.f) * wv;
  }
#pragma unroll
  for (int mask = 1; mask < 16; mask <<= 1)
#pragma unroll
    for (int g = 0; g < 4; ++g) pg[g] += __shfl_xor(pg[g], mask);
  if (r16 == 0) {
#pragma unroll
    for (int g = 0; g < 4; ++g) part[rt * 16 + quad * 4 + g][ch] = pg[g];
  }
  __syncthreads();
  if (t < 32) {
    float sv = part[t][0] + part[t][1];
    pbuf[m0 + t] = 1.f / (1.f + __expf(-sv));
  }
}

// ---------------- edge prediction ----------------
__global__ void pred_kernel(const float* __restrict__ p, const int* __restrict__ eli,
                            float* __restrict__ out, int K) {
  int i = blockIdx.x * blockDim.x + threadIdx.x;
  if (i < K) out[i] = p[eli[i]] * p[eli[K + i]];
}

extern "C" void kernel_launch(void* const* d_in, const int* in_sizes, int n_in,
                              void* d_out, int out_size, void* d_ws, size_t ws_size,
                              hipStream_t stream) {
  const float* x       = (const float*)d_in[0];
  const float* seq     = (const float*)d_in[1];
  const int* src       = (const int*)d_in[2];
  const int* dst       = (const int*)d_in[3];
  const int* eli       = (const int*)d_in[4];
  const float* skip_w0 = (const float*)d_in[5];
  const float* skip_b0 = (const float*)d_in[6];
  const float* msg_w0  = (const float*)d_in[7];
  const float* msg_b0  = (const float*)d_in[8];
  const float* skip_w1 = (const float*)d_in[9];
  const float* skip_b1 = (const float*)d_in[10];
  const float* msg_w1  = (const float*)d_in[11];
  const float* msg_b1  = (const float*)d_in[12];
  const float* ipw     = (const float*)d_in[13];
  const float* ipb     = (const float*)d_in[14];
  const float* opw     = (const float*)d_in[15];
  const float* opb     = (const float*)d_in[16];
  const float* ln_g    = (const float*)d_in[17];
  const float* ln_b    = (const float*)d_in[18];
  const float* w1      = (const float*)d_in[19];
  const float* w2      = (const float*)d_in[20];

  const int N  = in_sizes[0] / D;   // 8192
  const int S  = in_sizes[1] / D;   // 2048
  const int E  = in_sizes[2];       // 524288
  const int Kp = in_sizes[4] / 2;   // 100000

  float* ws    = (float*)d_ws;
  float* B2    = ws;                              // gcn2 out fp32 (residual)
  float* Osp   = B2 + (size_t)N * D;              // 4 * N * D split outputs
  short* xbf   = (short*)(Osp + 4 * (size_t)N * D);
  short* Abf   = xbf + (size_t)N * D;             // agg out (reused both layers)
  short* B1bf  = Abf + (size_t)N * D;             // gcn1 out bf16
  short* Qbf   = B1bf + (size_t)N * D;
  short* Kbf   = Qbf + (size_t)N * D;
  short* Vt    = Kbf + (size_t)S * D;
  short* Wbf   = Vt + (size_t)D * S;              // 9 * 16384
  float* qn    = (float*)(Wbf + 9 * 16384);       // 4*N
  float* lbuf  = qn + 4 * (size_t)N;              // 16*N
  float* dinv  = lbuf + 16 * (size_t)N;
  float* pbuf  = dinv + N;
  int*   MkhI  = (int*)(pbuf + N);                // 4
  int* deg     = MkhI + 4;                        // N
  int* row_ptr = deg + N;                         // N+1
  int* csr_src = row_ptr + (N + 1);               // E
  int* histd   = csr_src + E;                     // HB*8192
  int* hists   = histd + HB * 8192;               // HB*8192
  int* base_arr= hists + HB * 8192;               // HB*8192

  float* pred_out = (float*)d_out;
  float* emb_out  = pred_out + Kp;

  const short* w_skip0 = Wbf + 0 * 16384;
  const short* w_msg0  = Wbf + 1 * 16384;
  const short* w_skip1 = Wbf + 2 * 16384;
  const short* w_msg1  = Wbf + 3 * 16384;
  const short* w_q     = Wbf + 4 * 16384;
  const short* w_k     = Wbf + 5 * 16384;
  const short* w_v     = Wbf + 6 * 16384;
  const short* w_op    = Wbf + 7 * 16384;
  const short* w_m1    = Wbf + 8 * 16384;

  hipMemsetAsync(MkhI, 0, 4 * sizeof(int), stream);

  WSrc wsrc;
  wsrc.p[0] = skip_w0; wsrc.p[1] = msg_w0; wsrc.p[2] = skip_w1; wsrc.p[3] = msg_w1;
  wsrc.p[4] = ipw; wsrc.p[5] = ipw + D * D; wsrc.p[6] = ipw + 2 * D * D;
  wsrc.p[7] = opw; wsrc.p[8] = w1;
  prep0_kernel<<<144 + (N * D / 1024), 256, 0, stream>>>(wsrc, (short*)Wbf, x, xbf);

  // atomic-free CSR build
  hist_kernel<<<HB, 256, 0, stream>>>(src, dst, histd, hists, E);
  colsum_kernel<<<N / 256, 256, 0, stream>>>(histd, hists, deg, dinv);
  scan8k_kernel<<<1, 1024, 0, stream>>>(deg, row_ptr, N);
  basegen_kernel<<<N / 256, 256, 0, stream>>>(histd, row_ptr, base_arr);
  scatter2_kernel<<<HB, 256, 0, stream>>>(src, dst, base_arr, csr_src, E);

  // GCN layers (bf16 gather, dual MFMA GEMMs)
  agg_kernel<<<N, 128, 0, stream>>>(xbf, dinv, row_ptr, csr_src, Abf);
  gemm_gcn_kernel<<<N / 32, 256, 0, stream>>>(Abf, w_msg0, msg_b0, xbf, w_skip0, skip_b0, B1bf, nullptr);
  agg_kernel<<<N, 128, 0, stream>>>(B1bf, dinv, row_ptr, csr_src, Abf);
  gemm_gcn_kernel<<<N / 32, 256, 0, stream>>>(Abf, w_msg1, msg_b1, B1bf, w_skip1, skip_b1, nullptr, B2);

  // fused QKV projections + attention prep
  qkv_kernel<<<N / 32 + 2 * (S / 32), 256, 0, stream>>>(
      B2, seq, w_q, w_k, w_v, ipb, Qbf, qn, Kbf, MkhI, Vt, N, S);

  // attention: split-S=4, plain stores, merge fused into out_proj GEMM
  dim3 fgrid(N / 32, 4, 4);
  flash_kernel<<<fgrid, 64, 0, stream>>>(Qbf, Kbf, Vt, qn, MkhI, Osp, lbuf, N, S);
  gemm_op_kernel<<<N / 32, 256, 0, stream>>>(Osp, lbuf, w_op, opb, B2, ln_g, ln_b, emb_out, N);

  // MLP (+sigmoid) and prediction
  gemm_mlp_kernel<<<N / 32, 256, 0, stream>>>(emb_out, w_m1, w2, pbuf);
  pred_kernel<<<(Kp + 255) / 256, 256, 0, stream>>>(pbuf, eli, pred_out, Kp);
}